// Round 2
// baseline (1930.873 us; speedup 1.0000x reference)
//
#include <hip/hip_runtime.h>
#include <hip/hip_bf16.h>
#include <math.h>

#define BATCH 32
#define NNEUR 1000
#define NSTATE 64
#define INDIM 1024
#define HID 1024

typedef short bf16x8 __attribute__((ext_vector_type(8)));
typedef float f32x4 __attribute__((ext_vector_type(4)));

__device__ __forceinline__ float sigmoidf_(float x){ return 1.0f/(1.0f + __expf(-x)); }
__device__ __forceinline__ float tanhf_(float x){
  float ax = fabsf(x);
  float e = __expf(-2.0f*ax);
  float r = (1.0f - e)/(1.0f + e);
  return copysignf(r, x);
}
__device__ __forceinline__ unsigned short f2bf(float x){
  unsigned u = __float_as_uint(x);
  unsigned r = (u + 0x7FFFu + ((u>>16)&1u)) >> 16;
  return (unsigned short)r;
}

// ---------------- K1: ns = x@W_emb.T + b_emb ; fb = sigmoid(x@W_inproj.T + b_inproj)
__global__ __launch_bounds__(256) void k1_emb(const float* __restrict__ x,
    const float* __restrict__ W_emb, const float* __restrict__ b_emb,
    const float* __restrict__ W_inp, const float* __restrict__ b_inp,
    float* __restrict__ ns, float* __restrict__ fb)
{
  __shared__ __align__(16) float xl[BATCH][256];
  __shared__ float red[16][33];
  const int tid = threadIdx.x;
  const int jin = tid >> 4;   // 0..15
  const int seg = tid & 15;   // 0..15
  const int j0 = blockIdx.x * 16;
  int j = j0 + jin;
  const float* wrow;
  if (j < 64000) wrow = W_emb + (size_t)j * INDIM;
  else { int jj = j - 64000; if (jj > 999) jj = 999; wrow = W_inp + (size_t)jj * INDIM; }
  float acc[BATCH];
  #pragma unroll
  for (int b=0;b<BATCH;b++) acc[b]=0.f;
  for (int c=0;c<4;c++){
    __syncthreads();
    for (int f = tid; f < (BATCH*256/4); f += 256){
      int b = f >> 6; int col = (f & 63) << 2;
      *(float4*)&xl[b][col] = *(const float4*)&x[b*INDIM + c*256 + col];
    }
    __syncthreads();
    #pragma unroll
    for (int ii=0; ii<4; ii++){
      float4 wv = *(const float4*)&wrow[c*256 + ii*64 + seg*4];
      #pragma unroll
      for (int b=0;b<BATCH;b++){
        float4 xv = *(const float4*)&xl[b][ii*64 + seg*4];
        acc[b] = fmaf(wv.x, xv.x, acc[b]);
        acc[b] = fmaf(wv.y, xv.y, acc[b]);
        acc[b] = fmaf(wv.z, xv.z, acc[b]);
        acc[b] = fmaf(wv.w, xv.w, acc[b]);
      }
    }
  }
  #pragma unroll
  for (int b=0;b<BATCH;b++){
    float v = acc[b];
    v += __shfl_xor(v, 1);
    v += __shfl_xor(v, 2);
    v += __shfl_xor(v, 4);
    v += __shfl_xor(v, 8);
    acc[b] = v;
  }
  __syncthreads();
  if (seg == 0){
    #pragma unroll
    for (int b=0;b<BATCH;b++) red[jin][b] = acc[b];
  }
  __syncthreads();
  #pragma unroll
  for (int r=0;r<2;r++){
    int jj = tid & 15;
    int b = (tid >> 4) + r*16;
    int jg = j0 + jj;
    float v = red[jj][b];
    if (jg < 64000){
      ns[(size_t)b*64000 + jg] = v + b_emb[jg];
    } else if (jg < 65000){
      fb[b*1000 + (jg-64000)] = sigmoidf_(v + b_inp[jg-64000]);
    }
  }
}

// ---------------- K2: pre[rn][j] = ns[rn,:]@w_ih[j,:] + b_ih[j] + b_hh[j]
// 500 blocks x 64 rows; w_ih row in regs per thread; ns tile in LDS (broadcast reads).
__global__ __launch_bounds__(256) void k2_pre(const float* __restrict__ ns,
   const float* __restrict__ w_ih, const float* __restrict__ b_ih, const float* __restrict__ b_hh,
   float* __restrict__ pre)
{
  __shared__ __align__(16) float nsl[64*64];   // 16KB
  const int tid = threadIdx.x;
  const int j = tid;
  const int rn0 = blockIdx.x * 64;
  float wreg[64];
  const float* wr = w_ih + j*64;
  #pragma unroll
  for (int k=0;k<64;k+=4){
    float4 v = *(const float4*)&wr[k];
    wreg[k]=v.x; wreg[k+1]=v.y; wreg[k+2]=v.z; wreg[k+3]=v.w;
  }
  float bias = b_ih[j] + b_hh[j];
  const float4* src = (const float4*)(ns + (size_t)rn0*64);
  for (int i=tid; i<64*16; i+=256) ((float4*)nsl)[i] = src[i];
  __syncthreads();
  for (int r=0;r<64;r++){
    float a0=0,a1=0,a2=0,a3=0;
    #pragma unroll
    for (int k=0;k<64;k+=4){
      float4 nv = *(const float4*)&nsl[r*64+k];
      a0=fmaf(nv.x,wreg[k],a0);   a1=fmaf(nv.y,wreg[k+1],a1);
      a2=fmaf(nv.z,wreg[k+2],a2); a3=fmaf(nv.w,wreg[k+3],a3);
    }
    pre[(size_t)(rn0+r)*256 + j] = (a0+a1)+(a2+a3) + bias;
  }
}

// ---------------- K3: blocks 0..1 = MFMA LSTM (16 batches each); blocks 2..126 = SDE+conv
// LSTM: per step, G^T[256 x 16] = w_hh(bf16 A-frags, regs) x H^T(bf16, LDS), C-init = pre tile.
// Wave w owns j in [16w,16w+16): computes i,f,g,o tiles for that j-slice -> c,h in registers.
__global__ __launch_bounds__(256) void k3_lstm_sde(
  const float* __restrict__ pre, float* __restrict__ lstm_out,
  const float* __restrict__ w_hh,
  const float* __restrict__ noise, const float* __restrict__ fb,
  const float* __restrict__ conv_w, const float* __restrict__ decay_p,
  float* __restrict__ S0, float* __restrict__ S1, float* __restrict__ S2)
{
  __shared__ __align__(16) float sh[2048];   // 8KB, aliased per branch
  const int tid = threadIdx.x;
  if (blockIdx.x < 2){
    // ---- MFMA LSTM ----
    unsigned short (*hp)[8][16][8] = (unsigned short (*)[8][16][8])sh; // [2][8chunk][16n][8] bf16
    const int b0 = blockIdx.x * 16;
    const int w = tid >> 6;          // wave 0..3: j-slice [16w,16w+16)
    const int lane = tid & 63;
    const int nl = lane & 15;        // A-row m / B-col n / D-col (batch-local)
    const int g  = lane >> 4;        // frag k-group / D-row-group
    // zero both h buffers
    for (int i = tid; i < 2*8*16*8; i += 256) ((unsigned short*)hp)[i] = 0;
    // A-frags: A[m,k] = w_hh[64*gt + 16*w + m][kh*32 + 8g + jj]  (bf16)
    bf16x8 A[4][2];
    #pragma unroll
    for (int gt=0; gt<4; gt++){
      #pragma unroll
      for (int kh=0; kh<2; kh++){
        const float* srcw = w_hh + (size_t)(gt*64 + w*16 + nl)*64 + kh*32 + g*8;
        bf16x8 f;
        #pragma unroll
        for (int jj=0;jj<8;jj++) f[jj] = (short)f2bf(srcw[jj]);
        A[gt][kh] = f;
      }
    }
    float c[4] = {0.f,0.f,0.f,0.f};
    // pre[b0+nl][t][gt*64 + 16w + 4g + q]
    const float* pbase = pre + (size_t)(b0+nl)*256000 + w*16 + g*4;
    f32x4 P[4];
    #pragma unroll
    for (int gt=0;gt<4;gt++) P[gt] = *(const f32x4*)(pbase + gt*64);
    float* lbase = lstm_out + (size_t)(b0+nl)*64000 + w*16 + g*4;
    const int cj = 2*w + (g>>1);
    const int su = 4*(g&1);
    __syncthreads();
    int cur = 0;
    for (int t=0; t<1000; t++){
      bf16x8 B0 = *(const bf16x8*)hp[cur][g][nl];
      bf16x8 B1 = *(const bf16x8*)hp[cur][4+g][nl];
      int tn = (t < 999) ? (t+1) : 999;
      f32x4 Pn[4];
      #pragma unroll
      for (int gt=0;gt<4;gt++) Pn[gt] = *(const f32x4*)(pbase + (size_t)tn*256 + gt*64);
      f32x4 D[4];
      #pragma unroll
      for (int gt=0;gt<4;gt++){
        D[gt] = __builtin_amdgcn_mfma_f32_16x16x32_bf16(A[gt][0], B0, P[gt], 0,0,0);
        D[gt] = __builtin_amdgcn_mfma_f32_16x16x32_bf16(A[gt][1], B1, D[gt], 0,0,0);
      }
      float h[4];
      #pragma unroll
      for (int q=0;q<4;q++){
        float iv = sigmoidf_(D[0][q]);
        float fv = sigmoidf_(D[1][q]);
        float gv = tanhf_(D[2][q]);
        float ov = sigmoidf_(D[3][q]);
        c[q] = fv*c[q] + iv*gv;
        h[q] = ov * tanhf_(c[q]);
      }
      *(f32x4*)(lbase + (size_t)t*64) = (f32x4){h[0],h[1],h[2],h[3]};
      unsigned lo = (unsigned)f2bf(h[0]) | ((unsigned)f2bf(h[1])<<16);
      unsigned hi = (unsigned)f2bf(h[2]) | ((unsigned)f2bf(h[3])<<16);
      unsigned* dst = (unsigned*)&hp[1-cur][cj][nl][su];
      dst[0] = lo; dst[1] = hi;
      #pragma unroll
      for (int gt=0;gt<4;gt++) P[gt] = Pn[gt];
      __syncthreads();
      cur ^= 1;
    }
  } else {
    // ---- SDE + fused conv ----
    float* cw = sh;            // 641*3 = 1923 floats
    for (int f = tid; f < 641*3; f += 256) cw[f] = conv_w[f];
    __syncthreads();
    int idx = (blockIdx.x - 2)*256 + tid;   // < 32000
    int b = idx / 1000, n = idx - b*1000;
    float fcoef = fb[b*1000 + (n/100)];
    float dr = decay_p[0];
    const float dt = 1.0f/640.0f;
    float adec = 1.0f - dr*dt;
    float g = fcoef * sqrtf(dt);
    const float* nptr = noise + (size_t)idx * 640;
    float X=0.f, s0=0.f, s1=0.f, s2=0.f;
    for (int t0=0;t0<640;t0+=4){
      float4 nz = *(const float4*)&nptr[t0];
      float nv[4] = {nz.x, nz.y, nz.z, nz.w};
      #pragma unroll
      for (int u=0;u<4;u++){
        X = fmaf(adec, X, g*nv[u]);
        int t = t0 + u + 1;
        s0 = fmaf(cw[t*3+0], X, s0);
        s1 = fmaf(cw[t*3+1], X, s1);
        s2 = fmaf(cw[t*3+2], X, s2);
      }
    }
    S0[idx]=s0; S1[idx]=s1; S2[idx]=s2;
  }
}

// ---------------- K4: qkv projection. 256 blocks x 128 rows; w_in staged in LDS (broadcast).
// thread = (row rl 0..127, half dh): dh=0 -> w rows 0..95, dh=1 -> 96..191.
__global__ __launch_bounds__(256) void k4_qkv(const float* __restrict__ lstm_out,
  const float* __restrict__ w_in, const float* __restrict__ b_in,
  unsigned short* __restrict__ Qb, unsigned short* __restrict__ Kb, unsigned short* __restrict__ Vt)
{
  __shared__ __align__(16) float wl[192*64];   // 48KB
  __shared__ float bl[192];
  const int tid = threadIdx.x;
  for (int i=tid;i<3072;i+=256) ((float4*)wl)[i] = ((const float4*)w_in)[i];
  if (tid < 192) bl[tid] = b_in[tid];
  __syncthreads();
  const int rl = tid & 127, dh = tid >> 7;
  const int rn = blockIdx.x*128 + rl;         // 0..32767, never crosses a batch
  const int b = rn >> 10, n = rn & 1023;
  const bool valid = (n < 1000);
  float row[64];
  if (valid){
    const float* lr = lstm_out + ((size_t)b*1000 + n)*64;
    #pragma unroll
    for (int k=0;k<64;k+=4){
      float4 v = *(const float4*)&lr[k];
      row[k]=v.x; row[k+1]=v.y; row[k+2]=v.z; row[k+3]=v.w;
    }
  } else {
    #pragma unroll
    for (int k=0;k<64;k++) row[k]=0.f;
  }
  for (int dc=0; dc<12; dc++){
    const int d0 = dh*96 + dc*8;
    float acc[8];
    #pragma unroll
    for (int u=0;u<8;u++) acc[u] = bl[d0+u];
    #pragma unroll
    for (int k=0;k<64;k+=4){
      float4 rv = *(const float4*)&row[k];
      #pragma unroll
      for (int u=0;u<8;u++){
        float4 wv = *(const float4*)&wl[(d0+u)*64 + k];
        acc[u]=fmaf(rv.x,wv.x,acc[u]); acc[u]=fmaf(rv.y,wv.y,acc[u]);
        acc[u]=fmaf(rv.z,wv.z,acc[u]); acc[u]=fmaf(rv.w,wv.w,acc[u]);
      }
    }
    unsigned short pk[8];
    #pragma unroll
    for (int u=0;u<8;u++) pk[u] = valid ? f2bf(acc[u]) : (unsigned short)0;
    if (d0 + 8 <= 64){
      *(bf16x8*)&Qb[(size_t)rn*64 + d0] = *(bf16x8*)pk;
    } else if (d0 + 8 <= 128){
      *(bf16x8*)&Kb[(size_t)rn*64 + (d0-64)] = *(bf16x8*)pk;
    } else {
      int dv = d0 - 128;
      #pragma unroll
      for (int u=0;u<8;u++) Vt[((size_t)b*64 + dv+u)*1024 + n] = pk[u];
    }
  }
}

// ---------------- K5: attention (unchanged)
__global__ __launch_bounds__(256) void k5_attn(
  const unsigned short* __restrict__ Qb, const unsigned short* __restrict__ Kb,
  const unsigned short* __restrict__ Vt,
  float* __restrict__ attn_w, float* __restrict__ ctx)
{
  const int b = blockIdx.x;
  const int qblk = blockIdx.y;
  const int wid = threadIdx.x >> 6;
  const int lane = threadIdx.x & 63;
  const int r = lane & 15, gq = lane >> 4;
  const int q0 = qblk*64 + wid*16;
  const int q = q0 + r;
  const bool gok = (gq < 2);
  const float scale = 0.25f;
  const f32x4 z4 = {0.f,0.f,0.f,0.f};

  bf16x8 qf[4];
  #pragma unroll
  for (int h=0; h<4; h++){
    bf16x8 f = {};
    if (gok) f = *(const bf16x8*)&Qb[(((size_t)b*1024)+q)*64 + h*16 + 8*gq];
    qf[h] = f;
  }
  float sinv[4];
  #pragma unroll
  for (int h=0; h<4; h++){
    float es = 0.f;
    for (int kk=0; kk<63; kk++){
      bf16x8 kf = {};
      if (gok) kf = *(const bf16x8*)&Kb[(((size_t)b*1024)+(kk*16+r))*64 + h*16 + 8*gq];
      f32x4 d = __builtin_amdgcn_mfma_f32_16x16x32_bf16(kf, qf[h], z4, 0,0,0);
      float e0=__expf(d[0]*scale), e1=__expf(d[1]*scale), e2=__expf(d[2]*scale), e3=__expf(d[3]*scale);
      if (kk == 62 && !gok){ e0=0;e1=0;e2=0;e3=0; }
      es += (e0+e1)+(e2+e3);
    }
    es += __shfl_xor(es, 16);
    es += __shfl_xor(es, 32);
    sinv[h] = 1.0f / es;
  }
  f32x4 cacc[4] = {};
  float* awrow = attn_w + (size_t)b*1000000;
  for (int kk=0; kk<63; kk++){
    f32x4 aacc = z4;
    #pragma unroll
    for (int h=0; h<4; h++){
      bf16x8 kf = {};
      if (gok) kf = *(const bf16x8*)&Kb[(((size_t)b*1024)+(kk*16+r))*64 + h*16 + 8*gq];
      f32x4 d = __builtin_amdgcn_mfma_f32_16x16x32_bf16(kf, qf[h], z4, 0,0,0);
      float p0=__expf(d[0]*scale)*sinv[h], p1=__expf(d[1]*scale)*sinv[h];
      float p2=__expf(d[2]*scale)*sinv[h], p3=__expf(d[3]*scale)*sinv[h];
      if (kk == 62 && !gok){ p0=0;p1=0;p2=0;p3=0; }
      aacc[0] += 0.25f*p0; aacc[1] += 0.25f*p1; aacc[2] += 0.25f*p2; aacc[3] += 0.25f*p3;
      unsigned p01 = (unsigned)f2bf(p0) | ((unsigned)f2bf(p1) << 16);
      unsigned p23 = (unsigned)f2bf(p2) | ((unsigned)f2bf(p3) << 16);
      int slo = (r + 32*gq) & 63;
      int shi = (slo + 16) & 63;
      int b0 = __shfl((int)p01, slo), b1 = __shfl((int)p23, slo);
      int b2 = __shfl((int)p01, shi), b3 = __shfl((int)p23, shi);
      union { int i[4]; bf16x8 v; } pu;
      pu.i[0]=b0; pu.i[1]=b1; pu.i[2]=b2; pu.i[3]=b3;
      bf16x8 pfrag = pu.v;
      if (!gok) pfrag = (bf16x8){};
      bf16x8 vf = {};
      if (gok) vf = *(const bf16x8*)&Vt[(((size_t)b*64) + h*16 + r)*1024 + kk*16 + 8*gq];
      cacc[h] = __builtin_amdgcn_mfma_f32_16x16x32_bf16(vf, pfrag, cacc[h], 0,0,0);
    }
    int kbase = kk*16 + 4*gq;
    if (q < 1000 && !(kk==62 && !gok)){
      *(f32x4*)&awrow[(size_t)q*1000 + kbase] = aacc;
    }
  }
  if (q < 1000){
    #pragma unroll
    for (int h=0; h<4; h++){
      *(f32x4*)&ctx[(((size_t)b*1024)+q)*64 + h*16 + 4*gq] = cacc[h];
    }
  }
}

// ---------------- K6: enn = relu((sum_n ctx)@w_out.T/1000 + b_out) @ W_fix.T
__global__ __launch_bounds__(256) void k6_enn(const float* __restrict__ ctx,
  const float* __restrict__ w_out, const float* __restrict__ b_out,
  const float* __restrict__ W_fix, float* __restrict__ enn_out)
{
  __shared__ __align__(16) float csum[64];
  __shared__ __align__(16) float epre[64];
  __shared__ float part[256];
  int b = blockIdx.x, t = threadIdx.x;
  int d = t & 63, sg = t >> 6;
  float s0=0,s1=0;
  int nbeg = sg*250, nend = nbeg+250;
  for (int n=nbeg; n<nend; n+=2){
    s0 += ctx[(((size_t)b*1024)+n)*64 + d];
    s1 += ctx[(((size_t)b*1024)+n+1)*64 + d];
  }
  part[t] = s0+s1;
  __syncthreads();
  if (t < 64) csum[t] = part[t] + part[64+t] + part[128+t] + part[192+t];
  __syncthreads();
  if (t < 64){
    const float* wr = w_out + t*64;
    float a = 0;
    #pragma unroll
    for (int k=0;k<64;k++) a = fmaf(csum[k], wr[k], a);
    epre[t] = fmaxf(a*(1.0f/1000.0f) + b_out[t], 0.0f);
  }
  __syncthreads();
  for (int m = t; m < 1024; m += 256){
    const float* fr = W_fix + m*64;
    float a = 0;
    #pragma unroll
    for (int k=0;k<64;k+=4){
      float4 e4 = *(const float4*)&epre[k];
      float4 f4 = *(const float4*)&fr[k];
      a=fmaf(e4.x,f4.x,a); a=fmaf(e4.y,f4.y,a); a=fmaf(e4.z,f4.z,a); a=fmaf(e4.w,f4.w,a);
    }
    enn_out[b*1024 + m] = a;
  }
}

// ---------------- K7: agg = shifted sums of S0/S1/S2 + conv_b
__global__ __launch_bounds__(256) void k7_agg(const float* __restrict__ S0, const float* __restrict__ S1,
  const float* __restrict__ S2, const float* __restrict__ conv_b, float* __restrict__ agg)
{
  int i = blockIdx.x*256 + threadIdx.x;
  if (i >= 32000) return;
  int n = i % 1000;
  float v = S1[i] + conv_b[0];
  if (n > 0)   v += S0[i-1];
  if (n < 999) v += S2[i+1];
  agg[i] = v;
}

// ---------------- K8: bicep = agg@W_bout.T + b_bout
__global__ __launch_bounds__(64) void k8_bicep(const float* __restrict__ agg,
  const float* __restrict__ W_bout, const float* __restrict__ b_bout, float* __restrict__ bicep)
{
  int gt = blockIdx.x*64 + threadIdx.x;
  int bb = gt & 31, m = gt >> 5;
  const float* wr = W_bout + (size_t)m*1000;
  const float* ar = agg + bb*1000;
  float a = 0;
  for (int n=0;n<1000;n+=4){
    float4 w4 = *(const float4*)&wr[n];
    float4 a4 = *(const float4*)&ar[n];
    a=fmaf(w4.x,a4.x,a); a=fmaf(w4.y,a4.y,a); a=fmaf(w4.z,a4.z,a); a=fmaf(w4.w,a4.w,a);
  }
  bicep[bb*1024 + m] = a + b_bout[m];
}

// ---------------- K9: fused = [enn,bicep]@W_fuse.T + b_fuse
__global__ __launch_bounds__(64) void k9_fuse(const float* __restrict__ enn, const float* __restrict__ bic,
  const float* __restrict__ W_fuse, const float* __restrict__ b_fuse, float* __restrict__ fused)
{
  int gt = blockIdx.x*64 + threadIdx.x;
  int bb = gt & 31, m = gt >> 5;
  const float* er = enn + bb*1024;
  const float* br = bic + bb*1024;
  const float* wr = W_fuse + (size_t)m*2048;
  float a = 0;
  for (int jj=0;jj<1024;jj+=4){
    float4 e4 = *(const float4*)&er[jj];
    float4 w4 = *(const float4*)&wr[jj];
    a=fmaf(e4.x,w4.x,a); a=fmaf(e4.y,w4.y,a); a=fmaf(e4.z,w4.z,a); a=fmaf(e4.w,w4.w,a);
  }
  for (int jj=0;jj<1024;jj+=4){
    float4 b4 = *(const float4*)&br[jj];
    float4 w4 = *(const float4*)&wr[1024+jj];
    a=fmaf(b4.x,w4.x,a); a=fmaf(b4.y,w4.y,a); a=fmaf(b4.z,w4.z,a); a=fmaf(b4.w,w4.w,a);
  }
  fused[bb*1024 + m] = a + b_fuse[m];
}

// ---------------- K10: output = fused@W_proj.T + b_proj
__global__ __launch_bounds__(64) void k10_proj(const float* __restrict__ fused,
  const float* __restrict__ W_proj, const float* __restrict__ b_proj, float* __restrict__ outp)
{
  int gt = blockIdx.x*64 + threadIdx.x;
  int bb = gt & 31, m = gt >> 5;
  const float* fr = fused + bb*1024;
  const float* wr = W_proj + (size_t)m*1024;
  float a = 0;
  for (int jj=0;jj<1024;jj+=4){
    float4 f4 = *(const float4*)&fr[jj];
    float4 w4 = *(const float4*)&wr[jj];
    a=fmaf(f4.x,w4.x,a); a=fmaf(f4.y,w4.y,a); a=fmaf(f4.z,w4.z,a); a=fmaf(f4.w,w4.w,a);
  }
  outp[bb*1024 + m] = a + b_proj[m];
}

extern "C" void kernel_launch(void* const* d_in, const int* in_sizes, int n_in,
                              void* d_out, int out_size, void* d_ws, size_t ws_size,
                              hipStream_t stream)
{
  const float* x       = (const float*)d_in[0];
  const float* noise   = (const float*)d_in[1];
  const float* W_emb   = (const float*)d_in[2];
  const float* b_emb   = (const float*)d_in[3];
  const float* w_ih    = (const float*)d_in[4];
  const float* w_hh    = (const float*)d_in[5];
  const float* b_ih    = (const float*)d_in[6];
  const float* b_hh    = (const float*)d_in[7];
  const float* w_in    = (const float*)d_in[8];
  const float* b_in    = (const float*)d_in[9];
  const float* w_out   = (const float*)d_in[10];
  const float* b_out   = (const float*)d_in[11];
  const float* W_fix   = (const float*)d_in[12];
  const float* W_inp   = (const float*)d_in[13];
  const float* b_inp   = (const float*)d_in[14];
  const float* conv_w  = (const float*)d_in[15];
  const float* conv_b  = (const float*)d_in[16];
  const float* W_bout  = (const float*)d_in[17];
  const float* b_bout  = (const float*)d_in[18];
  const float* decay   = (const float*)d_in[19];
  const float* W_fuse  = (const float*)d_in[20];
  const float* b_fuse  = (const float*)d_in[21];
  const float* W_proj  = (const float*)d_in[22];
  const float* b_proj  = (const float*)d_in[23];

  float* out       = (float*)d_out;
  float* enn_out   = out + 32768;
  float* bicep_out = out + 65536;
  float* attn_out  = out + 98304;

  float* ws    = (float*)d_ws;
  float* fb    = ws;                    // 32000
  float* ns    = ws + 32000;            // 2,048,000
  float* pre   = ws + 2080000;          // 8,192,000
  float* lstm  = ws + 10272000;         // 2,048,000
  float* ctx   = ws + 12320000;         // 2,097,152
  float* S0    = ws + 14417152;         // 32000
  float* S1    = ws + 14449152;
  float* S2    = ws + 14481152;
  float* agg   = ws + 14513152;
  float* fused = ws + 14545152;         // 32768
  unsigned short* Qb = (unsigned short*)(ws + 14577920);  // 2,097,152 u16 each
  unsigned short* Kb = Qb + 2097152;
  unsigned short* Vt = Kb + 2097152;

  k1_emb<<<4063, 256, 0, stream>>>(x, W_emb, b_emb, W_inp, b_inp, ns, fb);
  k2_pre<<<500, 256, 0, stream>>>(ns, w_ih, b_ih, b_hh, pre);
  k3_lstm_sde<<<127, 256, 0, stream>>>(pre, lstm, w_hh, noise, fb, conv_w, decay, S0, S1, S2);
  k4_qkv<<<256, 256, 0, stream>>>(lstm, w_in, b_in, Qb, Kb, Vt);
  k5_attn<<<dim3(32,16), 256, 0, stream>>>(Qb, Kb, Vt, attn_out, ctx);
  k6_enn<<<32, 256, 0, stream>>>(ctx, w_out, b_out, W_fix, enn_out);
  k7_agg<<<126, 256, 0, stream>>>(S0, S1, S2, conv_b, agg);
  k8_bicep<<<512, 64, 0, stream>>>(agg, W_bout, b_bout, bicep_out);
  k9_fuse<<<512, 64, 0, stream>>>(enn_out, bicep_out, W_fuse, b_fuse, fused);
  k10_proj<<<512, 64, 0, stream>>>(fused, W_proj, b_proj, out);
}

// Round 3
// 1483.880 us; speedup vs baseline: 1.3012x; 1.3012x over previous
//
#include <hip/hip_runtime.h>
#include <hip/hip_bf16.h>
#include <math.h>

#define BATCH 32
#define NNEUR 1000
#define NSTATE 64
#define INDIM 1024
#define HID 1024

typedef short bf16x8 __attribute__((ext_vector_type(8)));
typedef float f32x4 __attribute__((ext_vector_type(4)));

__device__ __forceinline__ float sigmoidf_(float x){ return 1.0f/(1.0f + __expf(-x)); }
__device__ __forceinline__ unsigned short f2bf(float x){
  unsigned u = __float_as_uint(x);
  unsigned r = (u + 0x7FFFu + ((u>>16)&1u)) >> 16;
  return (unsigned short)r;
}
// saturation-safe fast sigmoid/tanh via v_exp_f32 (exp2) + v_rcp_f32.
// x->-inf: exp2(+inf)=inf, rcp(inf)=0 -> 0 ; x->+inf: exp2(-inf)=0 -> 1. No NaN.
__device__ __forceinline__ float sig2(float x){
  return __builtin_amdgcn_rcpf(1.0f + __builtin_amdgcn_exp2f(x * -1.44269504f));
}
__device__ __forceinline__ float tanh2(float x){
  return 1.0f - 2.0f*__builtin_amdgcn_rcpf(1.0f + __builtin_amdgcn_exp2f(x * 2.88539008f));
}

// ---------------- K1: ns = x@W_emb.T + b_emb ; fb = sigmoid(x@W_inproj.T + b_inproj)
__global__ __launch_bounds__(256) void k1_emb(const float* __restrict__ x,
    const float* __restrict__ W_emb, const float* __restrict__ b_emb,
    const float* __restrict__ W_inp, const float* __restrict__ b_inp,
    float* __restrict__ ns, float* __restrict__ fb)
{
  __shared__ __align__(16) float xl[BATCH][256];
  __shared__ float red[16][33];
  const int tid = threadIdx.x;
  const int jin = tid >> 4;   // 0..15
  const int seg = tid & 15;   // 0..15
  const int j0 = blockIdx.x * 16;
  int j = j0 + jin;
  const float* wrow;
  if (j < 64000) wrow = W_emb + (size_t)j * INDIM;
  else { int jj = j - 64000; if (jj > 999) jj = 999; wrow = W_inp + (size_t)jj * INDIM; }
  float acc[BATCH];
  #pragma unroll
  for (int b=0;b<BATCH;b++) acc[b]=0.f;
  for (int c=0;c<4;c++){
    __syncthreads();
    for (int f = tid; f < (BATCH*256/4); f += 256){
      int b = f >> 6; int col = (f & 63) << 2;
      *(float4*)&xl[b][col] = *(const float4*)&x[b*INDIM + c*256 + col];
    }
    __syncthreads();
    #pragma unroll
    for (int ii=0; ii<4; ii++){
      float4 wv = *(const float4*)&wrow[c*256 + ii*64 + seg*4];
      #pragma unroll
      for (int b=0;b<BATCH;b++){
        float4 xv = *(const float4*)&xl[b][ii*64 + seg*4];
        acc[b] = fmaf(wv.x, xv.x, acc[b]);
        acc[b] = fmaf(wv.y, xv.y, acc[b]);
        acc[b] = fmaf(wv.z, xv.z, acc[b]);
        acc[b] = fmaf(wv.w, xv.w, acc[b]);
      }
    }
  }
  #pragma unroll
  for (int b=0;b<BATCH;b++){
    float v = acc[b];
    v += __shfl_xor(v, 1);
    v += __shfl_xor(v, 2);
    v += __shfl_xor(v, 4);
    v += __shfl_xor(v, 8);
    acc[b] = v;
  }
  __syncthreads();
  if (seg == 0){
    #pragma unroll
    for (int b=0;b<BATCH;b++) red[jin][b] = acc[b];
  }
  __syncthreads();
  #pragma unroll
  for (int r=0;r<2;r++){
    int jj = tid & 15;
    int b = (tid >> 4) + r*16;
    int jg = j0 + jj;
    float v = red[jj][b];
    if (jg < 64000){
      ns[(size_t)b*64000 + jg] = v + b_emb[jg];
    } else if (jg < 65000){
      fb[b*1000 + (jg-64000)] = sigmoidf_(v + b_inp[jg-64000]);
    }
  }
}

// ---------------- K2: pre[rn][perm(j)] = ns[rn,:]@w_ih[j,:] + b_ih[j] + b_hh[j]
// Permuted store: col = jj*4 + gate (gate-interleaved) for k3's MFMA C-init.
__global__ __launch_bounds__(256) void k2_pre(const float* __restrict__ ns,
   const float* __restrict__ w_ih, const float* __restrict__ b_ih, const float* __restrict__ b_hh,
   float* __restrict__ pre)
{
  __shared__ __align__(16) float nsl[64*64];   // 16KB
  const int tid = threadIdx.x;
  const int j = tid;                 // original gate-row 0..255
  const int rn0 = blockIdx.x * 64;
  const int pcol = (j & 63)*4 + (j >> 6);   // permuted column
  float wreg[64];
  const float* wr = w_ih + j*64;
  #pragma unroll
  for (int k=0;k<64;k+=4){
    float4 v = *(const float4*)&wr[k];
    wreg[k]=v.x; wreg[k+1]=v.y; wreg[k+2]=v.z; wreg[k+3]=v.w;
  }
  float bias = b_ih[j] + b_hh[j];
  const float4* src = (const float4*)(ns + (size_t)rn0*64);
  for (int i=tid; i<64*16; i+=256) ((float4*)nsl)[i] = src[i];
  __syncthreads();
  for (int r=0;r<64;r++){
    float a0=0,a1=0,a2=0,a3=0;
    #pragma unroll
    for (int k=0;k<64;k+=4){
      float4 nv = *(const float4*)&nsl[r*64+k];
      a0=fmaf(nv.x,wreg[k],a0);   a1=fmaf(nv.y,wreg[k+1],a1);
      a2=fmaf(nv.z,wreg[k+2],a2); a3=fmaf(nv.w,wreg[k+3],a3);
    }
    pre[(size_t)(rn0+r)*256 + pcol] = (a0+a1)+(a2+a3) + bias;
  }
}

// ---------------- K3: blocks 0..1 = MFMA LSTM (1024 thr, 16 waves, 16 batches);
//                     blocks 2..33 = SDE+conv (1024 thr)
// LSTM wave rt owns js {4rt..4rt+3}. Row-permuted w_hh: row r = 4*jl + gate.
// D reg q of lane (nl,g) = gate q pre-act for j=4rt+g, batch b0+nl.
// Drain-free step: raw s_barrier + lgkmcnt(0) only; pre prefetch depth-2;
// h history stored fire-and-forget; h exchanged via swizzled bf16 LDS (dbuf).
__global__ __launch_bounds__(1024) void k3_lstm_sde(
  const float* __restrict__ pre, float* __restrict__ lstm_out,
  const float* __restrict__ w_hh,
  const float* __restrict__ noise, const float* __restrict__ fb,
  const float* __restrict__ conv_w, const float* __restrict__ decay_p,
  float* __restrict__ S0, float* __restrict__ S1, float* __restrict__ S2)
{
  __shared__ __align__(16) unsigned char shraw[8192];
  const int tid = threadIdx.x;
  if (blockIdx.x < 2){
    unsigned short (*hl)[16][80] = (unsigned short (*)[16][80])shraw;  // [2][16][80] bf16
    const int b0 = blockIdx.x * 16;
    const int rt = tid >> 6;          // wave = tile 0..15
    const int lane = tid & 63;
    const int nl = lane & 15;
    const int g  = lane >> 4;
    for (int i = tid; i < 2*16*80; i += 1024) ((unsigned short*)hl)[i] = 0;
    // A-frags: permuted row m=nl of tile rt -> w_hh[(nl&3)*64 + 4rt + (nl>>2)]
    const int orow = (nl&3)*64 + 4*rt + (nl>>2);
    const float* wsrc = w_hh + (size_t)orow*64;
    bf16x8 A0, A1;
    #pragma unroll
    for (int i=0;i<8;i++){
      A0[i] = (short)f2bf(wsrc[8*g + i]);
      A1[i] = (short)f2bf(wsrc[32 + 8*g + i]);
    }
    const int j = 4*rt + g;
    const float* pbase = pre + (size_t)(b0+nl)*256000 + j*4;
    f32x4 P0 = *(const f32x4*)(pbase);
    f32x4 P1 = *(const f32x4*)(pbase + 256);
    float* lb = lstm_out + (size_t)(b0+nl)*64000 + j;
    // swizzled LDS columns (keeps ds_read_b128 16B-aligned, spreads banks)
    const int sw = nl & 7;
    const int rd0 = 8*(g ^ sw);          // B0: k = 8g..8g+7
    const int rd1 = 8*((4+g) ^ sw);      // B1: k = 32+8g..
    const int wcol = (j & 7) | (((j >> 3) ^ sw) << 3);
    float c = 0.f;
    __syncthreads();
    int buf = 0;
    for (int t=0; t<1000; t++){
      bf16x8 B0 = *(const bf16x8*)&hl[buf][nl][rd0];
      bf16x8 B1 = *(const bf16x8*)&hl[buf][nl][rd1];
      int tp = (t+2 < 1000) ? t+2 : 999;
      f32x4 P2 = *(const f32x4*)(pbase + (size_t)tp*256);
      f32x4 D = __builtin_amdgcn_mfma_f32_16x16x32_bf16(A0, B0, P0, 0,0,0);
      D = __builtin_amdgcn_mfma_f32_16x16x32_bf16(A1, B1, D, 0,0,0);
      float is = sig2(D[0]);
      float fs = sig2(D[1]);
      float gt = tanh2(D[2]);
      float os = sig2(D[3]);
      c = fs*c + is*gt;
      float h = os * tanh2(c);
      lb[(size_t)t*64] = h;                    // fire-and-forget history store
      hl[buf^1][nl][wcol] = f2bf(h);
      asm volatile("s_waitcnt lgkmcnt(0)" ::: "memory");
      __builtin_amdgcn_s_barrier();
      asm volatile("" ::: "memory");
      buf ^= 1;
      P0 = P1; P1 = P2;
    }
  } else {
    float* cw = (float*)shraw;        // 641*3 = 1923 floats
    for (int f = tid; f < 641*3; f += 1024) cw[f] = conv_w[f];
    __syncthreads();
    int idx = (blockIdx.x - 2)*1024 + tid;   // < 32768, guard 32000
    if (idx < 32000){
      int b = idx / 1000, n = idx - b*1000;
      float fcoef = fb[b*1000 + (n/100)];
      float dr = decay_p[0];
      const float dt = 1.0f/640.0f;
      float adec = 1.0f - dr*dt;
      float g = fcoef * sqrtf(dt);
      const float* nptr = noise + (size_t)idx * 640;
      float X=0.f, s0=0.f, s1=0.f, s2=0.f;
      for (int t0=0;t0<640;t0+=4){
        float4 nz = *(const float4*)&nptr[t0];
        float nv[4] = {nz.x, nz.y, nz.z, nz.w};
        #pragma unroll
        for (int u=0;u<4;u++){
          X = fmaf(adec, X, g*nv[u]);
          int t = t0 + u + 1;
          s0 = fmaf(cw[t*3+0], X, s0);
          s1 = fmaf(cw[t*3+1], X, s1);
          s2 = fmaf(cw[t*3+2], X, s2);
        }
      }
      S0[idx]=s0; S1[idx]=s1; S2[idx]=s2;
    }
  }
}

// ---------------- K4: qkv projection. 256 blocks x 128 rows; w_in staged in LDS (broadcast).
__global__ __launch_bounds__(256) void k4_qkv(const float* __restrict__ lstm_out,
  const float* __restrict__ w_in, const float* __restrict__ b_in,
  unsigned short* __restrict__ Qb, unsigned short* __restrict__ Kb, unsigned short* __restrict__ Vt)
{
  __shared__ __align__(16) float wl[192*64];   // 48KB
  __shared__ float bl[192];
  const int tid = threadIdx.x;
  for (int i=tid;i<3072;i+=256) ((float4*)wl)[i] = ((const float4*)w_in)[i];
  if (tid < 192) bl[tid] = b_in[tid];
  __syncthreads();
  const int rl = tid & 127, dh = tid >> 7;
  const int rn = blockIdx.x*128 + rl;         // 0..32767, never crosses a batch
  const int b = rn >> 10, n = rn & 1023;
  const bool valid = (n < 1000);
  float row[64];
  if (valid){
    const float* lr = lstm_out + ((size_t)b*1000 + n)*64;
    #pragma unroll
    for (int k=0;k<64;k+=4){
      float4 v = *(const float4*)&lr[k];
      row[k]=v.x; row[k+1]=v.y; row[k+2]=v.z; row[k+3]=v.w;
    }
  } else {
    #pragma unroll
    for (int k=0;k<64;k++) row[k]=0.f;
  }
  for (int dc=0; dc<12; dc++){
    const int d0 = dh*96 + dc*8;
    float acc[8];
    #pragma unroll
    for (int u=0;u<8;u++) acc[u] = bl[d0+u];
    #pragma unroll
    for (int k=0;k<64;k+=4){
      float4 rv = *(const float4*)&row[k];
      #pragma unroll
      for (int u=0;u<8;u++){
        float4 wv = *(const float4*)&wl[(d0+u)*64 + k];
        acc[u]=fmaf(rv.x,wv.x,acc[u]); acc[u]=fmaf(rv.y,wv.y,acc[u]);
        acc[u]=fmaf(rv.z,wv.z,acc[u]); acc[u]=fmaf(rv.w,wv.w,acc[u]);
      }
    }
    unsigned short pk[8];
    #pragma unroll
    for (int u=0;u<8;u++) pk[u] = valid ? f2bf(acc[u]) : (unsigned short)0;
    if (d0 + 8 <= 64){
      *(bf16x8*)&Qb[(size_t)rn*64 + d0] = *(bf16x8*)pk;
    } else if (d0 + 8 <= 128){
      *(bf16x8*)&Kb[(size_t)rn*64 + (d0-64)] = *(bf16x8*)pk;
    } else {
      int dv = d0 - 128;
      #pragma unroll
      for (int u=0;u<8;u++) Vt[((size_t)b*64 + dv+u)*1024 + n] = pk[u];
    }
  }
}

// ---------------- K5: attention
__global__ __launch_bounds__(256) void k5_attn(
  const unsigned short* __restrict__ Qb, const unsigned short* __restrict__ Kb,
  const unsigned short* __restrict__ Vt,
  float* __restrict__ attn_w, float* __restrict__ ctx)
{
  const int b = blockIdx.x;
  const int qblk = blockIdx.y;
  const int wid = threadIdx.x >> 6;
  const int lane = threadIdx.x & 63;
  const int r = lane & 15, gq = lane >> 4;
  const int q0 = qblk*64 + wid*16;
  const int q = q0 + r;
  const bool gok = (gq < 2);
  const float scale = 0.25f;
  const f32x4 z4 = {0.f,0.f,0.f,0.f};

  bf16x8 qf[4];
  #pragma unroll
  for (int h=0; h<4; h++){
    bf16x8 f = {};
    if (gok) f = *(const bf16x8*)&Qb[(((size_t)b*1024)+q)*64 + h*16 + 8*gq];
    qf[h] = f;
  }
  float sinv[4];
  #pragma unroll
  for (int h=0; h<4; h++){
    float es = 0.f;
    for (int kk=0; kk<63; kk++){
      bf16x8 kf = {};
      if (gok) kf = *(const bf16x8*)&Kb[(((size_t)b*1024)+(kk*16+r))*64 + h*16 + 8*gq];
      f32x4 d = __builtin_amdgcn_mfma_f32_16x16x32_bf16(kf, qf[h], z4, 0,0,0);
      float e0=__expf(d[0]*scale), e1=__expf(d[1]*scale), e2=__expf(d[2]*scale), e3=__expf(d[3]*scale);
      if (kk == 62 && !gok){ e0=0;e1=0;e2=0;e3=0; }
      es += (e0+e1)+(e2+e3);
    }
    es += __shfl_xor(es, 16);
    es += __shfl_xor(es, 32);
    sinv[h] = 1.0f / es;
  }
  f32x4 cacc[4] = {};
  float* awrow = attn_w + (size_t)b*1000000;
  for (int kk=0; kk<63; kk++){
    f32x4 aacc = z4;
    #pragma unroll
    for (int h=0; h<4; h++){
      bf16x8 kf = {};
      if (gok) kf = *(const bf16x8*)&Kb[(((size_t)b*1024)+(kk*16+r))*64 + h*16 + 8*gq];
      f32x4 d = __builtin_amdgcn_mfma_f32_16x16x32_bf16(kf, qf[h], z4, 0,0,0);
      float p0=__expf(d[0]*scale)*sinv[h], p1=__expf(d[1]*scale)*sinv[h];
      float p2=__expf(d[2]*scale)*sinv[h], p3=__expf(d[3]*scale)*sinv[h];
      if (kk == 62 && !gok){ p0=0;p1=0;p2=0;p3=0; }
      aacc[0] += 0.25f*p0; aacc[1] += 0.25f*p1; aacc[2] += 0.25f*p2; aacc[3] += 0.25f*p3;
      unsigned p01 = (unsigned)f2bf(p0) | ((unsigned)f2bf(p1) << 16);
      unsigned p23 = (unsigned)f2bf(p2) | ((unsigned)f2bf(p3) << 16);
      int slo = (r + 32*gq) & 63;
      int shi = (slo + 16) & 63;
      int b0 = __shfl((int)p01, slo), b1 = __shfl((int)p23, slo);
      int b2 = __shfl((int)p01, shi), b3 = __shfl((int)p23, shi);
      union { int i[4]; bf16x8 v; } pu;
      pu.i[0]=b0; pu.i[1]=b1; pu.i[2]=b2; pu.i[3]=b3;
      bf16x8 pfrag = pu.v;
      if (!gok) pfrag = (bf16x8){};
      bf16x8 vf = {};
      if (gok) vf = *(const bf16x8*)&Vt[(((size_t)b*64) + h*16 + r)*1024 + kk*16 + 8*gq];
      cacc[h] = __builtin_amdgcn_mfma_f32_16x16x32_bf16(vf, pfrag, cacc[h], 0,0,0);
    }
    int kbase = kk*16 + 4*gq;
    if (q < 1000 && !(kk==62 && !gok)){
      *(f32x4*)&awrow[(size_t)q*1000 + kbase] = aacc;
    }
  }
  if (q < 1000){
    #pragma unroll
    for (int h=0; h<4; h++){
      *(f32x4*)&ctx[(((size_t)b*1024)+q)*64 + h*16 + 4*gq] = cacc[h];
    }
  }
}

// ---------------- K6: enn = relu((sum_n ctx)@w_out.T/1000 + b_out) @ W_fix.T
__global__ __launch_bounds__(256) void k6_enn(const float* __restrict__ ctx,
  const float* __restrict__ w_out, const float* __restrict__ b_out,
  const float* __restrict__ W_fix, float* __restrict__ enn_out)
{
  __shared__ __align__(16) float csum[64];
  __shared__ __align__(16) float epre[64];
  __shared__ float part[256];
  int b = blockIdx.x, t = threadIdx.x;
  int d = t & 63, sg = t >> 6;
  float s0=0,s1=0;
  int nbeg = sg*250, nend = nbeg+250;
  for (int n=nbeg; n<nend; n+=2){
    s0 += ctx[(((size_t)b*1024)+n)*64 + d];
    s1 += ctx[(((size_t)b*1024)+n+1)*64 + d];
  }
  part[t] = s0+s1;
  __syncthreads();
  if (t < 64) csum[t] = part[t] + part[64+t] + part[128+t] + part[192+t];
  __syncthreads();
  if (t < 64){
    const float* wr = w_out + t*64;
    float a = 0;
    #pragma unroll
    for (int k=0;k<64;k++) a = fmaf(csum[k], wr[k], a);
    epre[t] = fmaxf(a*(1.0f/1000.0f) + b_out[t], 0.0f);
  }
  __syncthreads();
  for (int m = t; m < 1024; m += 256){
    const float* fr = W_fix + m*64;
    float a = 0;
    #pragma unroll
    for (int k=0;k<64;k+=4){
      float4 e4 = *(const float4*)&epre[k];
      float4 f4 = *(const float4*)&fr[k];
      a=fmaf(e4.x,f4.x,a); a=fmaf(e4.y,f4.y,a); a=fmaf(e4.z,f4.z,a); a=fmaf(e4.w,f4.w,a);
    }
    enn_out[b*1024 + m] = a;
  }
}

// ---------------- K7: agg = shifted sums of S0/S1/S2 + conv_b
__global__ __launch_bounds__(256) void k7_agg(const float* __restrict__ S0, const float* __restrict__ S1,
  const float* __restrict__ S2, const float* __restrict__ conv_b, float* __restrict__ agg)
{
  int i = blockIdx.x*256 + threadIdx.x;
  if (i >= 32000) return;
  int n = i % 1000;
  float v = S1[i] + conv_b[0];
  if (n > 0)   v += S0[i-1];
  if (n < 999) v += S2[i+1];
  agg[i] = v;
}

// ---------------- K8: bicep = agg@W_bout.T + b_bout
__global__ __launch_bounds__(64) void k8_bicep(const float* __restrict__ agg,
  const float* __restrict__ W_bout, const float* __restrict__ b_bout, float* __restrict__ bicep)
{
  int gt = blockIdx.x*64 + threadIdx.x;
  int bb = gt & 31, m = gt >> 5;
  const float* wr = W_bout + (size_t)m*1000;
  const float* ar = agg + bb*1000;
  float a = 0;
  for (int n=0;n<1000;n+=4){
    float4 w4 = *(const float4*)&wr[n];
    float4 a4 = *(const float4*)&ar[n];
    a=fmaf(w4.x,a4.x,a); a=fmaf(w4.y,a4.y,a); a=fmaf(w4.z,a4.z,a); a=fmaf(w4.w,a4.w,a);
  }
  bicep[bb*1024 + m] = a + b_bout[m];
}

// ---------------- K9: fused = [enn,bicep]@W_fuse.T + b_fuse
__global__ __launch_bounds__(64) void k9_fuse(const float* __restrict__ enn, const float* __restrict__ bic,
  const float* __restrict__ W_fuse, const float* __restrict__ b_fuse, float* __restrict__ fused)
{
  int gt = blockIdx.x*64 + threadIdx.x;
  int bb = gt & 31, m = gt >> 5;
  const float* er = enn + bb*1024;
  const float* br = bic + bb*1024;
  const float* wr = W_fuse + (size_t)m*2048;
  float a = 0;
  for (int jj=0;jj<1024;jj+=4){
    float4 e4 = *(const float4*)&er[jj];
    float4 w4 = *(const float4*)&wr[jj];
    a=fmaf(e4.x,w4.x,a); a=fmaf(e4.y,w4.y,a); a=fmaf(e4.z,w4.z,a); a=fmaf(e4.w,w4.w,a);
  }
  for (int jj=0;jj<1024;jj+=4){
    float4 b4 = *(const float4*)&br[jj];
    float4 w4 = *(const float4*)&wr[1024+jj];
    a=fmaf(b4.x,w4.x,a); a=fmaf(b4.y,w4.y,a); a=fmaf(b4.z,w4.z,a); a=fmaf(b4.w,w4.w,a);
  }
  fused[bb*1024 + m] = a + b_fuse[m];
}

// ---------------- K10: output = fused@W_proj.T + b_proj
__global__ __launch_bounds__(64) void k10_proj(const float* __restrict__ fused,
  const float* __restrict__ W_proj, const float* __restrict__ b_proj, float* __restrict__ outp)
{
  int gt = blockIdx.x*64 + threadIdx.x;
  int bb = gt & 31, m = gt >> 5;
  const float* fr = fused + bb*1024;
  const float* wr = W_proj + (size_t)m*1024;
  float a = 0;
  for (int jj=0;jj<1024;jj+=4){
    float4 f4 = *(const float4*)&fr[jj];
    float4 w4 = *(const float4*)&wr[jj];
    a=fmaf(f4.x,w4.x,a); a=fmaf(f4.y,w4.y,a); a=fmaf(f4.z,w4.z,a); a=fmaf(f4.w,w4.w,a);
  }
  outp[bb*1024 + m] = a + b_proj[m];
}

extern "C" void kernel_launch(void* const* d_in, const int* in_sizes, int n_in,
                              void* d_out, int out_size, void* d_ws, size_t ws_size,
                              hipStream_t stream)
{
  const float* x       = (const float*)d_in[0];
  const float* noise   = (const float*)d_in[1];
  const float* W_emb   = (const float*)d_in[2];
  const float* b_emb   = (const float*)d_in[3];
  const float* w_ih    = (const float*)d_in[4];
  const float* w_hh    = (const float*)d_in[5];
  const float* b_ih    = (const float*)d_in[6];
  const float* b_hh    = (const float*)d_in[7];
  const float* w_in    = (const float*)d_in[8];
  const float* b_in    = (const float*)d_in[9];
  const float* w_out   = (const float*)d_in[10];
  const float* b_out   = (const float*)d_in[11];
  const float* W_fix   = (const float*)d_in[12];
  const float* W_inp   = (const float*)d_in[13];
  const float* b_inp   = (const float*)d_in[14];
  const float* conv_w  = (const float*)d_in[15];
  const float* conv_b  = (const float*)d_in[16];
  const float* W_bout  = (const float*)d_in[17];
  const float* b_bout  = (const float*)d_in[18];
  const float* decay   = (const float*)d_in[19];
  const float* W_fuse  = (const float*)d_in[20];
  const float* b_fuse  = (const float*)d_in[21];
  const float* W_proj  = (const float*)d_in[22];
  const float* b_proj  = (const float*)d_in[23];

  float* out       = (float*)d_out;
  float* enn_out   = out + 32768;
  float* bicep_out = out + 65536;
  float* attn_out  = out + 98304;

  float* ws    = (float*)d_ws;
  float* fb    = ws;                    // 32000
  float* ns    = ws + 32000;            // 2,048,000
  float* pre   = ws + 2080000;          // 8,192,000
  float* lstm  = ws + 10272000;         // 2,048,000
  float* ctx   = ws + 12320000;         // 2,097,152
  float* S0    = ws + 14417152;         // 32000
  float* S1    = ws + 14449152;
  float* S2    = ws + 14481152;
  float* agg   = ws + 14513152;
  float* fused = ws + 14545152;         // 32768
  unsigned short* Qb = (unsigned short*)(ws + 14577920);  // 2,097,152 u16 each
  unsigned short* Kb = Qb + 2097152;
  unsigned short* Vt = Kb + 2097152;

  k1_emb<<<4063, 256, 0, stream>>>(x, W_emb, b_emb, W_inp, b_inp, ns, fb);
  k2_pre<<<500, 256, 0, stream>>>(ns, w_ih, b_ih, b_hh, pre);
  k3_lstm_sde<<<34, 1024, 0, stream>>>(pre, lstm, w_hh, noise, fb, conv_w, decay, S0, S1, S2);
  k4_qkv<<<256, 256, 0, stream>>>(lstm, w_in, b_in, Qb, Kb, Vt);
  k5_attn<<<dim3(32,16), 256, 0, stream>>>(Qb, Kb, Vt, attn_out, ctx);
  k6_enn<<<32, 256, 0, stream>>>(ctx, w_out, b_out, W_fix, enn_out);
  k7_agg<<<126, 256, 0, stream>>>(S0, S1, S2, conv_b, agg);
  k8_bicep<<<512, 64, 0, stream>>>(agg, W_bout, b_bout, bicep_out);
  k9_fuse<<<512, 64, 0, stream>>>(enn_out, bicep_out, W_fuse, b_fuse, fused);
  k10_proj<<<512, 64, 0, stream>>>(fused, W_proj, b_proj, out);
}

// Round 4
// 1151.060 us; speedup vs baseline: 1.6775x; 1.2891x over previous
//
#include <hip/hip_runtime.h>
#include <hip/hip_bf16.h>
#include <math.h>

#define BATCH 32
#define NNEUR 1000
#define NSTATE 64
#define INDIM 1024
#define HID 1024

typedef short bf16x8 __attribute__((ext_vector_type(8)));
typedef float f32x4 __attribute__((ext_vector_type(4)));

__device__ __forceinline__ float sigmoidf_(float x){ return 1.0f/(1.0f + __expf(-x)); }
__device__ __forceinline__ unsigned short f2bf(float x){
  unsigned u = __float_as_uint(x);
  unsigned r = (u + 0x7FFFu + ((u>>16)&1u)) >> 16;
  return (unsigned short)r;
}
// saturation-safe fast sigmoid/tanh via v_exp_f32 (exp2) + v_rcp_f32.
__device__ __forceinline__ float sig2(float x){
  return __builtin_amdgcn_rcpf(1.0f + __builtin_amdgcn_exp2f(x * -1.44269504f));
}
__device__ __forceinline__ float tanh2(float x){
  return 1.0f - 2.0f*__builtin_amdgcn_rcpf(1.0f + __builtin_amdgcn_exp2f(x * 2.88539008f));
}
__device__ __forceinline__ f32x4 unpk4(uint2 p){
  f32x4 r;
  r[0] = __uint_as_float(p.x << 16);
  r[1] = __uint_as_float(p.x & 0xffff0000u);
  r[2] = __uint_as_float(p.y << 16);
  r[3] = __uint_as_float(p.y & 0xffff0000u);
  return r;
}

// ---------------- K1: ns = x@W_emb.T + b_emb ; fb = sigmoid(x@W_inproj.T + b_inproj)
__global__ __launch_bounds__(256) void k1_emb(const float* __restrict__ x,
    const float* __restrict__ W_emb, const float* __restrict__ b_emb,
    const float* __restrict__ W_inp, const float* __restrict__ b_inp,
    float* __restrict__ ns, float* __restrict__ fb)
{
  __shared__ __align__(16) float xl[BATCH][256];
  __shared__ float red[16][33];
  const int tid = threadIdx.x;
  const int jin = tid >> 4;   // 0..15
  const int seg = tid & 15;   // 0..15
  const int j0 = blockIdx.x * 16;
  int j = j0 + jin;
  const float* wrow;
  if (j < 64000) wrow = W_emb + (size_t)j * INDIM;
  else { int jj = j - 64000; if (jj > 999) jj = 999; wrow = W_inp + (size_t)jj * INDIM; }
  float acc[BATCH];
  #pragma unroll
  for (int b=0;b<BATCH;b++) acc[b]=0.f;
  for (int c=0;c<4;c++){
    __syncthreads();
    for (int f = tid; f < (BATCH*256/4); f += 256){
      int b = f >> 6; int col = (f & 63) << 2;
      *(float4*)&xl[b][col] = *(const float4*)&x[b*INDIM + c*256 + col];
    }
    __syncthreads();
    #pragma unroll
    for (int ii=0; ii<4; ii++){
      float4 wv = *(const float4*)&wrow[c*256 + ii*64 + seg*4];
      #pragma unroll
      for (int b=0;b<BATCH;b++){
        float4 xv = *(const float4*)&xl[b][ii*64 + seg*4];
        acc[b] = fmaf(wv.x, xv.x, acc[b]);
        acc[b] = fmaf(wv.y, xv.y, acc[b]);
        acc[b] = fmaf(wv.z, xv.z, acc[b]);
        acc[b] = fmaf(wv.w, xv.w, acc[b]);
      }
    }
  }
  #pragma unroll
  for (int b=0;b<BATCH;b++){
    float v = acc[b];
    v += __shfl_xor(v, 1);
    v += __shfl_xor(v, 2);
    v += __shfl_xor(v, 4);
    v += __shfl_xor(v, 8);
    acc[b] = v;
  }
  __syncthreads();
  if (seg == 0){
    #pragma unroll
    for (int b=0;b<BATCH;b++) red[jin][b] = acc[b];
  }
  __syncthreads();
  #pragma unroll
  for (int r=0;r<2;r++){
    int jj = tid & 15;
    int b = (tid >> 4) + r*16;
    int jg = j0 + jj;
    float v = red[jj][b];
    if (jg < 64000){
      ns[(size_t)b*64000 + jg] = v + b_emb[jg];
    } else if (jg < 65000){
      fb[b*1000 + (jg-64000)] = sigmoidf_(v + b_inp[jg-64000]);
    }
  }
}

// ---------------- K2: preh[rn][perm(j)] = bf16( ns[rn,:]@w_ih[j,:] + b_ih[j] + b_hh[j] )
// Permuted store: col = jl*4 + gate (gate-interleaved), bf16.
__global__ __launch_bounds__(256) void k2_pre(const float* __restrict__ ns,
   const float* __restrict__ w_ih, const float* __restrict__ b_ih, const float* __restrict__ b_hh,
   unsigned short* __restrict__ preh)
{
  __shared__ __align__(16) float nsl[64*64];   // 16KB
  const int tid = threadIdx.x;
  const int j = tid;                 // original gate-row 0..255 (gate = j>>6, jl = j&63)
  const int rn0 = blockIdx.x * 64;
  const int pcol = (j & 63)*4 + (j >> 6);
  float wreg[64];
  const float* wr = w_ih + j*64;
  #pragma unroll
  for (int k=0;k<64;k+=4){
    float4 v = *(const float4*)&wr[k];
    wreg[k]=v.x; wreg[k+1]=v.y; wreg[k+2]=v.z; wreg[k+3]=v.w;
  }
  float bias = b_ih[j] + b_hh[j];
  const float4* src = (const float4*)(ns + (size_t)rn0*64);
  for (int i=tid; i<64*16; i+=256) ((float4*)nsl)[i] = src[i];
  __syncthreads();
  for (int r=0;r<64;r++){
    float a0=0,a1=0,a2=0,a3=0;
    #pragma unroll
    for (int k=0;k<64;k+=4){
      float4 nv = *(const float4*)&nsl[r*64+k];
      a0=fmaf(nv.x,wreg[k],a0);   a1=fmaf(nv.y,wreg[k+1],a1);
      a2=fmaf(nv.z,wreg[k+2],a2); a3=fmaf(nv.w,wreg[k+3],a3);
    }
    preh[(size_t)(rn0+r)*256 + pcol] = f2bf((a0+a1)+(a2+a3) + bias);
  }
}

// ---------------- K3: blocks 0..1 = MFMA LSTM (512 thr, 8 waves, 16 batches each);
//                     blocks 2..64 = SDE+conv (512 thr)
// Wave w owns tiles 2w,2w+1 (j = 8w..8w+7); lane (nl,g) -> batch nl, j1=8w+g, j2=8w+4+g.
// h matrix [16 batch][64 j] bf16 in LDS, 128B rows, 16B-block XOR swizzle (^ nl&7).
// pre is bf16, depth-4 prefetch; history stored bf16, transposed [b][j][t], 8-step bursts.
__global__ __launch_bounds__(512) void k3_lstm_sde(
  const unsigned short* __restrict__ preh, unsigned short* __restrict__ lstmT,
  const float* __restrict__ w_hh,
  const float* __restrict__ noise, const float* __restrict__ fb,
  const float* __restrict__ conv_w, const float* __restrict__ decay_p,
  float* __restrict__ S0, float* __restrict__ S1, float* __restrict__ S2)
{
  __shared__ __align__(16) unsigned char shraw[8192];
  const int tid = threadIdx.x;
  if (blockIdx.x < 2){
    unsigned short* hls = (unsigned short*)shraw;   // [2][16][64] bf16
    const int b0 = blockIdx.x * 16;
    const int w = tid >> 6;          // wave 0..7
    const int lane = tid & 63;
    const int nl = lane & 15;        // batch-local
    const int g  = lane >> 4;        // 0..3
    const int sw = nl & 7;
    for (int i = tid; i < 2048; i += 512) hls[i] = 0;
    // A-frags for tiles rt=2w+tt: permuted row m=nl -> w_hh[(nl&3)*64 + 4rt + (nl>>2)]
    bf16x8 A[2][2];
    #pragma unroll
    for (int tt=0; tt<2; tt++){
      const int rt = 2*w + tt;
      const float* wsrc = w_hh + (size_t)((nl&3)*64 + 4*rt + (nl>>2))*64;
      #pragma unroll
      for (int kh=0; kh<2; kh++){
        bf16x8 f;
        #pragma unroll
        for (int i=0;i<8;i++) f[i] = (short)f2bf(wsrc[kh*32 + 8*g + i]);
        A[tt][kh] = f;
      }
    }
    const int j1 = 8*w + g, j2 = 8*w + 4 + g;
    const unsigned short* pb1 = preh + (size_t)(b0+nl)*256000 + j1*4;
    const unsigned short* pb2 = preh + (size_t)(b0+nl)*256000 + j2*4;
    uint2 Pa[4], Pb[4];
    #pragma unroll
    for (int s=0;s<4;s++){
      Pa[s] = *(const uint2*)(pb1 + (size_t)s*256);
      Pb[s] = *(const uint2*)(pb2 + (size_t)s*256);
    }
    // LDS short-offsets (row nl = 64 shorts = 128B; 16B block = 8 shorts)
    const int rdA = nl*64 + (g^sw)*8;        // B0: logical k-block g
    const int rdB = nl*64 + ((4+g)^sw)*8;    // B1: logical k-block 4+g
    const int wr1 = nl*64 + (w^sw)*8 + g;    // j1: block j1>>3 = w, offset g
    const int wr2 = nl*64 + (w^sw)*8 + 4+g;  // j2: same block, offset 4+g
    unsigned short* lt1 = lstmT + ((size_t)(b0+nl)*64 + j1)*1000;
    unsigned short* lt2 = lstmT + ((size_t)(b0+nl)*64 + j2)*1000;
    float c1 = 0.f, c2 = 0.f;
    unsigned ph1[4], ph2[4];
    __syncthreads();
    int buf = 0;
    for (int tb=0; tb<1000; tb+=8){
      #pragma unroll
      for (int u=0;u<8;u++){
        bf16x8 B0 = *(const bf16x8*)&hls[buf*1024 + rdA];
        bf16x8 B1 = *(const bf16x8*)&hls[buf*1024 + rdB];
        const int slot = u & 3;
        f32x4 C1 = unpk4(Pa[slot]);
        f32x4 C2 = unpk4(Pb[slot]);
        int tp = tb + u + 4; if (tp > 999) tp = 999;
        Pa[slot] = *(const uint2*)(pb1 + (size_t)tp*256);
        Pb[slot] = *(const uint2*)(pb2 + (size_t)tp*256);
        f32x4 D1 = __builtin_amdgcn_mfma_f32_16x16x32_bf16(A[0][0], B0, C1, 0,0,0);
        D1 = __builtin_amdgcn_mfma_f32_16x16x32_bf16(A[0][1], B1, D1, 0,0,0);
        f32x4 D2 = __builtin_amdgcn_mfma_f32_16x16x32_bf16(A[1][0], B0, C2, 0,0,0);
        D2 = __builtin_amdgcn_mfma_f32_16x16x32_bf16(A[1][1], B1, D2, 0,0,0);
        float i1 = sig2(D1[0]), f1 = sig2(D1[1]), g1 = tanh2(D1[2]), o1 = sig2(D1[3]);
        c1 = f1*c1 + i1*g1;
        float h1 = o1 * tanh2(c1);
        float i2 = sig2(D2[0]), f2 = sig2(D2[1]), g2 = tanh2(D2[2]), o2 = sig2(D2[3]);
        c2 = f2*c2 + i2*g2;
        float h2 = o2 * tanh2(c2);
        unsigned hb1 = f2bf(h1), hb2 = f2bf(h2);
        if (u & 1){ ph1[u>>1] |= hb1 << 16; ph2[u>>1] |= hb2 << 16; }
        else      { ph1[u>>1]  = hb1;       ph2[u>>1]  = hb2; }
        hls[(buf^1)*1024 + wr1] = (unsigned short)hb1;
        hls[(buf^1)*1024 + wr2] = (unsigned short)hb2;
        asm volatile("s_waitcnt lgkmcnt(0)" ::: "memory");
        __builtin_amdgcn_s_barrier();
        asm volatile("" ::: "memory");
        buf ^= 1;
      }
      *(uint4*)(lt1 + tb) = make_uint4(ph1[0], ph1[1], ph1[2], ph1[3]);
      *(uint4*)(lt2 + tb) = make_uint4(ph2[0], ph2[1], ph2[2], ph2[3]);
    }
  } else {
    float* cw = (float*)shraw;        // 641*3 = 1923 floats
    for (int f = tid; f < 641*3; f += 512) cw[f] = conv_w[f];
    __syncthreads();
    int idx = (blockIdx.x - 2)*512 + tid;   // < 32256, guard 32000
    if (idx < 32000){
      int b = idx / 1000, n = idx - b*1000;
      float fcoef = fb[b*1000 + (n/100)];
      float dr = decay_p[0];
      const float dt = 1.0f/640.0f;
      float adec = 1.0f - dr*dt;
      float g = fcoef * sqrtf(dt);
      const float* nptr = noise + (size_t)idx * 640;
      float X=0.f, s0=0.f, s1=0.f, s2=0.f;
      for (int t0=0;t0<640;t0+=4){
        float4 nz = *(const float4*)&nptr[t0];
        float nv[4] = {nz.x, nz.y, nz.z, nz.w};
        #pragma unroll
        for (int u=0;u<4;u++){
          X = fmaf(adec, X, g*nv[u]);
          int t = t0 + u + 1;
          s0 = fmaf(cw[t*3+0], X, s0);
          s1 = fmaf(cw[t*3+1], X, s1);
          s2 = fmaf(cw[t*3+2], X, s2);
        }
      }
      S0[idx]=s0; S1[idx]=s1; S2[idx]=s2;
    }
  }
}

// ---------------- K4: qkv projection. lstm history is transposed bf16 [b][j][t].
__global__ __launch_bounds__(256) void k4_qkv(const unsigned short* __restrict__ lstmT,
  const float* __restrict__ w_in, const float* __restrict__ b_in,
  unsigned short* __restrict__ Qb, unsigned short* __restrict__ Kb, unsigned short* __restrict__ Vt)
{
  __shared__ __align__(16) float wl[192*64];   // 48KB
  __shared__ float bl[192];
  const int tid = threadIdx.x;
  for (int i=tid;i<3072;i+=256) ((float4*)wl)[i] = ((const float4*)w_in)[i];
  if (tid < 192) bl[tid] = b_in[tid];
  __syncthreads();
  const int rl = tid & 127, dh = tid >> 7;
  const int rn = blockIdx.x*128 + rl;         // never crosses a batch
  const int b = rn >> 10, n = rn & 1023;
  const bool valid = (n < 1000);
  const int nc = valid ? n : 999;
  float row[64];
  #pragma unroll
  for (int k=0;k<64;k++){
    unsigned v = lstmT[((size_t)b*64 + k)*1000 + nc];
    row[k] = valid ? __uint_as_float(v << 16) : 0.f;
  }
  for (int dc=0; dc<12; dc++){
    const int d0 = dh*96 + dc*8;
    float acc[8];
    #pragma unroll
    for (int u=0;u<8;u++) acc[u] = bl[d0+u];
    #pragma unroll
    for (int k=0;k<64;k+=4){
      float4 rv = *(const float4*)&row[k];
      #pragma unroll
      for (int u=0;u<8;u++){
        float4 wv = *(const float4*)&wl[(d0+u)*64 + k];
        acc[u]=fmaf(rv.x,wv.x,acc[u]); acc[u]=fmaf(rv.y,wv.y,acc[u]);
        acc[u]=fmaf(rv.z,wv.z,acc[u]); acc[u]=fmaf(rv.w,wv.w,acc[u]);
      }
    }
    unsigned short pk[8];
    #pragma unroll
    for (int u=0;u<8;u++) pk[u] = valid ? f2bf(acc[u]) : (unsigned short)0;
    if (d0 + 8 <= 64){
      *(bf16x8*)&Qb[(size_t)rn*64 + d0] = *(bf16x8*)pk;
    } else if (d0 + 8 <= 128){
      *(bf16x8*)&Kb[(size_t)rn*64 + (d0-64)] = *(bf16x8*)pk;
    } else {
      int dv = d0 - 128;
      #pragma unroll
      for (int u=0;u<8;u++) Vt[((size_t)b*64 + dv+u)*1024 + n] = pk[u];
    }
  }
}

// ---------------- K5: attention
__global__ __launch_bounds__(256) void k5_attn(
  const unsigned short* __restrict__ Qb, const unsigned short* __restrict__ Kb,
  const unsigned short* __restrict__ Vt,
  float* __restrict__ attn_w, float* __restrict__ ctx)
{
  const int b = blockIdx.x;
  const int qblk = blockIdx.y;
  const int wid = threadIdx.x >> 6;
  const int lane = threadIdx.x & 63;
  const int r = lane & 15, gq = lane >> 4;
  const int q0 = qblk*64 + wid*16;
  const int q = q0 + r;
  const bool gok = (gq < 2);
  const float scale = 0.25f;
  const f32x4 z4 = {0.f,0.f,0.f,0.f};

  bf16x8 qf[4];
  #pragma unroll
  for (int h=0; h<4; h++){
    bf16x8 f = {};
    if (gok) f = *(const bf16x8*)&Qb[(((size_t)b*1024)+q)*64 + h*16 + 8*gq];
    qf[h] = f;
  }
  float sinv[4];
  #pragma unroll
  for (int h=0; h<4; h++){
    float es = 0.f;
    for (int kk=0; kk<63; kk++){
      bf16x8 kf = {};
      if (gok) kf = *(const bf16x8*)&Kb[(((size_t)b*1024)+(kk*16+r))*64 + h*16 + 8*gq];
      f32x4 d = __builtin_amdgcn_mfma_f32_16x16x32_bf16(kf, qf[h], z4, 0,0,0);
      float e0=__expf(d[0]*scale), e1=__expf(d[1]*scale), e2=__expf(d[2]*scale), e3=__expf(d[3]*scale);
      if (kk == 62 && !gok){ e0=0;e1=0;e2=0;e3=0; }
      es += (e0+e1)+(e2+e3);
    }
    es += __shfl_xor(es, 16);
    es += __shfl_xor(es, 32);
    sinv[h] = 1.0f / es;
  }
  f32x4 cacc[4] = {};
  float* awrow = attn_w + (size_t)b*1000000;
  for (int kk=0; kk<63; kk++){
    f32x4 aacc = z4;
    #pragma unroll
    for (int h=0; h<4; h++){
      bf16x8 kf = {};
      if (gok) kf = *(const bf16x8*)&Kb[(((size_t)b*1024)+(kk*16+r))*64 + h*16 + 8*gq];
      f32x4 d = __builtin_amdgcn_mfma_f32_16x16x32_bf16(kf, qf[h], z4, 0,0,0);
      float p0=__expf(d[0]*scale)*sinv[h], p1=__expf(d[1]*scale)*sinv[h];
      float p2=__expf(d[2]*scale)*sinv[h], p3=__expf(d[3]*scale)*sinv[h];
      if (kk == 62 && !gok){ p0=0;p1=0;p2=0;p3=0; }
      aacc[0] += 0.25f*p0; aacc[1] += 0.25f*p1; aacc[2] += 0.25f*p2; aacc[3] += 0.25f*p3;
      unsigned p01 = (unsigned)f2bf(p0) | ((unsigned)f2bf(p1) << 16);
      unsigned p23 = (unsigned)f2bf(p2) | ((unsigned)f2bf(p3) << 16);
      int slo = (r + 32*gq) & 63;
      int shi = (slo + 16) & 63;
      int b0 = __shfl((int)p01, slo), b1 = __shfl((int)p23, slo);
      int b2 = __shfl((int)p01, shi), b3 = __shfl((int)p23, shi);
      union { int i[4]; bf16x8 v; } pu;
      pu.i[0]=b0; pu.i[1]=b1; pu.i[2]=b2; pu.i[3]=b3;
      bf16x8 pfrag = pu.v;
      if (!gok) pfrag = (bf16x8){};
      bf16x8 vf = {};
      if (gok) vf = *(const bf16x8*)&Vt[(((size_t)b*64) + h*16 + r)*1024 + kk*16 + 8*gq];
      cacc[h] = __builtin_amdgcn_mfma_f32_16x16x32_bf16(vf, pfrag, cacc[h], 0,0,0);
    }
    int kbase = kk*16 + 4*gq;
    if (q < 1000 && !(kk==62 && !gok)){
      *(f32x4*)&awrow[(size_t)q*1000 + kbase] = aacc;
    }
  }
  if (q < 1000){
    #pragma unroll
    for (int h=0; h<4; h++){
      *(f32x4*)&ctx[(((size_t)b*1024)+q)*64 + h*16 + 4*gq] = cacc[h];
    }
  }
}

// ---------------- K6: enn = relu((sum_n ctx)@w_out.T/1000 + b_out) @ W_fix.T
__global__ __launch_bounds__(256) void k6_enn(const float* __restrict__ ctx,
  const float* __restrict__ w_out, const float* __restrict__ b_out,
  const float* __restrict__ W_fix, float* __restrict__ enn_out)
{
  __shared__ __align__(16) float csum[64];
  __shared__ __align__(16) float epre[64];
  __shared__ float part[256];
  int b = blockIdx.x, t = threadIdx.x;
  int d = t & 63, sg = t >> 6;
  float s0=0,s1=0;
  int nbeg = sg*250, nend = nbeg+250;
  for (int n=nbeg; n<nend; n+=2){
    s0 += ctx[(((size_t)b*1024)+n)*64 + d];
    s1 += ctx[(((size_t)b*1024)+n+1)*64 + d];
  }
  part[t] = s0+s1;
  __syncthreads();
  if (t < 64) csum[t] = part[t] + part[64+t] + part[128+t] + part[192+t];
  __syncthreads();
  if (t < 64){
    const float* wr = w_out + t*64;
    float a = 0;
    #pragma unroll
    for (int k=0;k<64;k++) a = fmaf(csum[k], wr[k], a);
    epre[t] = fmaxf(a*(1.0f/1000.0f) + b_out[t], 0.0f);
  }
  __syncthreads();
  for (int m = t; m < 1024; m += 256){
    const float* fr = W_fix + m*64;
    float a = 0;
    #pragma unroll
    for (int k=0;k<64;k+=4){
      float4 e4 = *(const float4*)&epre[k];
      float4 f4 = *(const float4*)&fr[k];
      a=fmaf(e4.x,f4.x,a); a=fmaf(e4.y,f4.y,a); a=fmaf(e4.z,f4.z,a); a=fmaf(e4.w,f4.w,a);
    }
    enn_out[b*1024 + m] = a;
  }
}

// ---------------- K7: agg = shifted sums of S0/S1/S2 + conv_b
__global__ __launch_bounds__(256) void k7_agg(const float* __restrict__ S0, const float* __restrict__ S1,
  const float* __restrict__ S2, const float* __restrict__ conv_b, float* __restrict__ agg)
{
  int i = blockIdx.x*256 + threadIdx.x;
  if (i >= 32000) return;
  int n = i % 1000;
  float v = S1[i] + conv_b[0];
  if (n > 0)   v += S0[i-1];
  if (n < 999) v += S2[i+1];
  agg[i] = v;
}

// ---------------- K8: bicep = agg@W_bout.T + b_bout
__global__ __launch_bounds__(64) void k8_bicep(const float* __restrict__ agg,
  const float* __restrict__ W_bout, const float* __restrict__ b_bout, float* __restrict__ bicep)
{
  int gt = blockIdx.x*64 + threadIdx.x;
  int bb = gt & 31, m = gt >> 5;
  const float* wr = W_bout + (size_t)m*1000;
  const float* ar = agg + bb*1000;
  float a = 0;
  for (int n=0;n<1000;n+=4){
    float4 w4 = *(const float4*)&wr[n];
    float4 a4 = *(const float4*)&ar[n];
    a=fmaf(w4.x,a4.x,a); a=fmaf(w4.y,a4.y,a); a=fmaf(w4.z,a4.z,a); a=fmaf(w4.w,a4.w,a);
  }
  bicep[bb*1024 + m] = a + b_bout[m];
}

// ---------------- K9: fused = [enn,bicep]@W_fuse.T + b_fuse
__global__ __launch_bounds__(64) void k9_fuse(const float* __restrict__ enn, const float* __restrict__ bic,
  const float* __restrict__ W_fuse, const float* __restrict__ b_fuse, float* __restrict__ fused)
{
  int gt = blockIdx.x*64 + threadIdx.x;
  int bb = gt & 31, m = gt >> 5;
  const float* er = enn + bb*1024;
  const float* br = bic + bb*1024;
  const float* wr = W_fuse + (size_t)m*2048;
  float a = 0;
  for (int jj=0;jj<1024;jj+=4){
    float4 e4 = *(const float4*)&er[jj];
    float4 w4 = *(const float4*)&wr[jj];
    a=fmaf(e4.x,w4.x,a); a=fmaf(e4.y,w4.y,a); a=fmaf(e4.z,w4.z,a); a=fmaf(e4.w,w4.w,a);
  }
  for (int jj=0;jj<1024;jj+=4){
    float4 b4 = *(const float4*)&br[jj];
    float4 w4 = *(const float4*)&wr[1024+jj];
    a=fmaf(b4.x,w4.x,a); a=fmaf(b4.y,w4.y,a); a=fmaf(b4.z,w4.z,a); a=fmaf(b4.w,w4.w,a);
  }
  fused[bb*1024 + m] = a + b_fuse[m];
}

// ---------------- K10: output = fused@W_proj.T + b_proj
__global__ __launch_bounds__(64) void k10_proj(const float* __restrict__ fused,
  const float* __restrict__ W_proj, const float* __restrict__ b_proj, float* __restrict__ outp)
{
  int gt = blockIdx.x*64 + threadIdx.x;
  int bb = gt & 31, m = gt >> 5;
  const float* fr = fused + bb*1024;
  const float* wr = W_proj + (size_t)m*1024;
  float a = 0;
  for (int jj=0;jj<1024;jj+=4){
    float4 f4 = *(const float4*)&fr[jj];
    float4 w4 = *(const float4*)&wr[jj];
    a=fmaf(f4.x,w4.x,a); a=fmaf(f4.y,w4.y,a); a=fmaf(f4.z,w4.z,a); a=fmaf(f4.w,w4.w,a);
  }
  outp[bb*1024 + m] = a + b_proj[m];
}

extern "C" void kernel_launch(void* const* d_in, const int* in_sizes, int n_in,
                              void* d_out, int out_size, void* d_ws, size_t ws_size,
                              hipStream_t stream)
{
  const float* x       = (const float*)d_in[0];
  const float* noise   = (const float*)d_in[1];
  const float* W_emb   = (const float*)d_in[2];
  const float* b_emb   = (const float*)d_in[3];
  const float* w_ih    = (const float*)d_in[4];
  const float* w_hh    = (const float*)d_in[5];
  const float* b_ih    = (const float*)d_in[6];
  const float* b_hh    = (const float*)d_in[7];
  const float* w_in    = (const float*)d_in[8];
  const float* b_in    = (const float*)d_in[9];
  const float* w_out   = (const float*)d_in[10];
  const float* b_out   = (const float*)d_in[11];
  const float* W_fix   = (const float*)d_in[12];
  const float* W_inp   = (const float*)d_in[13];
  const float* b_inp   = (const float*)d_in[14];
  const float* conv_w  = (const float*)d_in[15];
  const float* conv_b  = (const float*)d_in[16];
  const float* W_bout  = (const float*)d_in[17];
  const float* b_bout  = (const float*)d_in[18];
  const float* decay   = (const float*)d_in[19];
  const float* W_fuse  = (const float*)d_in[20];
  const float* b_fuse  = (const float*)d_in[21];
  const float* W_proj  = (const float*)d_in[22];
  const float* b_proj  = (const float*)d_in[23];

  float* out       = (float*)d_out;
  float* enn_out   = out + 32768;
  float* bicep_out = out + 65536;
  float* attn_out  = out + 98304;

  float* ws    = (float*)d_ws;
  float* fb    = ws;                    // 32000
  float* ns    = ws + 32000;            // 2,048,000
  unsigned short* preh  = (unsigned short*)(ws + 2080000);   // 8,192,000 u16
  unsigned short* lstmT = (unsigned short*)(ws + 10272000);  // 2,048,000 u16
  float* ctx   = ws + 12320000;         // 2,097,152
  float* S0    = ws + 14417152;         // 32000
  float* S1    = ws + 14449152;
  float* S2    = ws + 14481152;
  float* agg   = ws + 14513152;
  float* fused = ws + 14545152;         // 32768
  unsigned short* Qb = (unsigned short*)(ws + 14577920);  // 2,097,152 u16 each
  unsigned short* Kb = Qb + 2097152;
  unsigned short* Vt = Kb + 2097152;

  k1_emb<<<4063, 256, 0, stream>>>(x, W_emb, b_emb, W_inp, b_inp, ns, fb);
  k2_pre<<<500, 256, 0, stream>>>(ns, w_ih, b_ih, b_hh, preh);
  k3_lstm_sde<<<65, 512, 0, stream>>>(preh, lstmT, w_hh, noise, fb, conv_w, decay, S0, S1, S2);
  k4_qkv<<<256, 256, 0, stream>>>(lstmT, w_in, b_in, Qb, Kb, Vt);
  k5_attn<<<dim3(32,16), 256, 0, stream>>>(Qb, Kb, Vt, attn_out, ctx);
  k6_enn<<<32, 256, 0, stream>>>(ctx, w_out, b_out, W_fix, enn_out);
  k7_agg<<<126, 256, 0, stream>>>(S0, S1, S2, conv_b, agg);
  k8_bicep<<<512, 64, 0, stream>>>(agg, W_bout, b_bout, bicep_out);
  k9_fuse<<<512, 64, 0, stream>>>(enn_out, bicep_out, W_fuse, b_fuse, fused);
  k10_proj<<<512, 64, 0, stream>>>(fused, W_proj, b_proj, out);
}

// Round 5
// 944.828 us; speedup vs baseline: 2.0436x; 1.2183x over previous
//
#include <hip/hip_runtime.h>
#include <hip/hip_bf16.h>
#include <math.h>

#define BATCH 32
#define NNEUR 1000
#define NSTATE 64
#define INDIM 1024
#define HID 1024

typedef short bf16x8 __attribute__((ext_vector_type(8)));
typedef float f32x4 __attribute__((ext_vector_type(4)));

__device__ __forceinline__ float sigmoidf_(float x){ return 1.0f/(1.0f + __expf(-x)); }
__device__ __forceinline__ unsigned short f2bf(float x){
  unsigned u = __float_as_uint(x);
  unsigned r = (u + 0x7FFFu + ((u>>16)&1u)) >> 16;
  return (unsigned short)r;
}
// saturation-safe fast sigmoid/tanh via v_exp_f32 (exp2) + v_rcp_f32.
__device__ __forceinline__ float sig2(float x){
  return __builtin_amdgcn_rcpf(1.0f + __builtin_amdgcn_exp2f(x * -1.44269504f));
}
__device__ __forceinline__ float tanh2(float x){
  return 1.0f - 2.0f*__builtin_amdgcn_rcpf(1.0f + __builtin_amdgcn_exp2f(x * 2.88539008f));
}
__device__ __forceinline__ f32x4 unpk4(uint2 p){
  f32x4 r;
  r[0] = __uint_as_float(p.x << 16);
  r[1] = __uint_as_float(p.x & 0xffff0000u);
  r[2] = __uint_as_float(p.y << 16);
  r[3] = __uint_as_float(p.y & 0xffff0000u);
  return r;
}

// ---------------- K1: ns = x@W_emb.T + b_emb ; fb = sigmoid(x@W_inproj.T + b_inproj)
__global__ __launch_bounds__(256) void k1_emb(const float* __restrict__ x,
    const float* __restrict__ W_emb, const float* __restrict__ b_emb,
    const float* __restrict__ W_inp, const float* __restrict__ b_inp,
    float* __restrict__ ns, float* __restrict__ fb)
{
  __shared__ __align__(16) float xl[BATCH][256];
  __shared__ float red[16][33];
  const int tid = threadIdx.x;
  const int jin = tid >> 4;   // 0..15
  const int seg = tid & 15;   // 0..15
  const int j0 = blockIdx.x * 16;
  int j = j0 + jin;
  const float* wrow;
  if (j < 64000) wrow = W_emb + (size_t)j * INDIM;
  else { int jj = j - 64000; if (jj > 999) jj = 999; wrow = W_inp + (size_t)jj * INDIM; }
  float acc[BATCH];
  #pragma unroll
  for (int b=0;b<BATCH;b++) acc[b]=0.f;
  for (int c=0;c<4;c++){
    __syncthreads();
    for (int f = tid; f < (BATCH*256/4); f += 256){
      int b = f >> 6; int col = (f & 63) << 2;
      *(float4*)&xl[b][col] = *(const float4*)&x[b*INDIM + c*256 + col];
    }
    __syncthreads();
    #pragma unroll
    for (int ii=0; ii<4; ii++){
      float4 wv = *(const float4*)&wrow[c*256 + ii*64 + seg*4];
      #pragma unroll
      for (int b=0;b<BATCH;b++){
        float4 xv = *(const float4*)&xl[b][ii*64 + seg*4];
        acc[b] = fmaf(wv.x, xv.x, acc[b]);
        acc[b] = fmaf(wv.y, xv.y, acc[b]);
        acc[b] = fmaf(wv.z, xv.z, acc[b]);
        acc[b] = fmaf(wv.w, xv.w, acc[b]);
      }
    }
  }
  #pragma unroll
  for (int b=0;b<BATCH;b++){
    float v = acc[b];
    v += __shfl_xor(v, 1);
    v += __shfl_xor(v, 2);
    v += __shfl_xor(v, 4);
    v += __shfl_xor(v, 8);
    acc[b] = v;
  }
  __syncthreads();
  if (seg == 0){
    #pragma unroll
    for (int b=0;b<BATCH;b++) red[jin][b] = acc[b];
  }
  __syncthreads();
  #pragma unroll
  for (int r=0;r<2;r++){
    int jj = tid & 15;
    int b = (tid >> 4) + r*16;
    int jg = j0 + jj;
    float v = red[jj][b];
    if (jg < 64000){
      ns[(size_t)b*64000 + jg] = v + b_emb[jg];
    } else if (jg < 65000){
      fb[b*1000 + (jg-64000)] = sigmoidf_(v + b_inp[jg-64000]);
    }
  }
}

// ---------------- K2: preh[rn][perm(j)] = bf16( ns[rn,:]@w_ih[j,:] + b_ih[j] + b_hh[j] )
__global__ __launch_bounds__(256) void k2_pre(const float* __restrict__ ns,
   const float* __restrict__ w_ih, const float* __restrict__ b_ih, const float* __restrict__ b_hh,
   unsigned short* __restrict__ preh)
{
  __shared__ __align__(16) float nsl[64*64];   // 16KB
  const int tid = threadIdx.x;
  const int j = tid;                 // original gate-row 0..255 (gate = j>>6, jl = j&63)
  const int rn0 = blockIdx.x * 64;
  const int pcol = (j & 63)*4 + (j >> 6);
  float wreg[64];
  const float* wr = w_ih + j*64;
  #pragma unroll
  for (int k=0;k<64;k+=4){
    float4 v = *(const float4*)&wr[k];
    wreg[k]=v.x; wreg[k+1]=v.y; wreg[k+2]=v.z; wreg[k+3]=v.w;
  }
  float bias = b_ih[j] + b_hh[j];
  const float4* src = (const float4*)(ns + (size_t)rn0*64);
  for (int i=tid; i<64*16; i+=256) ((float4*)nsl)[i] = src[i];
  __syncthreads();
  for (int r=0;r<64;r++){
    float a0=0,a1=0,a2=0,a3=0;
    #pragma unroll
    for (int k=0;k<64;k+=4){
      float4 nv = *(const float4*)&nsl[r*64+k];
      a0=fmaf(nv.x,wreg[k],a0);   a1=fmaf(nv.y,wreg[k+1],a1);
      a2=fmaf(nv.z,wreg[k+2],a2); a3=fmaf(nv.w,wreg[k+3],a3);
    }
    preh[(size_t)(rn0+r)*256 + pcol] = f2bf((a0+a1)+(a2+a3) + bias);
  }
}

// ---------------- K3: blocks 0..7 = MFMA LSTM (512 thr, 8 waves, 4 batches each);
//                     blocks 8..70 = SDE+conv (512 thr)
// Wave w owns tiles 2w,2w+1 (j = 8w..8w+7). MFMA uses only B cols 0..3 (4 batches).
// Cell spread: lanes nl<4 -> (batch nl, j1) from own D1; lanes 4..7 -> (batch nl-4, j2)
// via 4-dword shfl of D2 (c-state resident in owning lane). Lanes >=8 masked.
__global__ __launch_bounds__(512) void k3_lstm_sde(
  const unsigned short* __restrict__ preh, unsigned short* __restrict__ lstmT,
  const float* __restrict__ w_hh,
  const float* __restrict__ noise, const float* __restrict__ fb,
  const float* __restrict__ conv_w, const float* __restrict__ decay_p,
  float* __restrict__ S0, float* __restrict__ S1, float* __restrict__ S2)
{
  __shared__ __align__(16) unsigned char shraw[8192];
  const int tid = threadIdx.x;
  if (blockIdx.x < 8){
    unsigned short* hls = (unsigned short*)shraw;   // [2][16][64] bf16
    const int b0 = blockIdx.x * 4;
    const int w = tid >> 6;          // wave 0..7
    const int lane = tid & 63;
    const int nl = lane & 15;
    const int g  = lane >> 4;        // 0..3
    const int sw = nl & 7;
    for (int i = tid; i < 2048; i += 512) hls[i] = 0;
    // A-frags for tiles rt=2w+tt: permuted row m=nl -> w_hh[(nl&3)*64 + 4rt + (nl>>2)]
    bf16x8 A[2][2];
    #pragma unroll
    for (int tt=0; tt<2; tt++){
      const int rt = 2*w + tt;
      const float* wsrc = w_hh + (size_t)((nl&3)*64 + 4*rt + (nl>>2))*64;
      #pragma unroll
      for (int kh=0; kh<2; kh++){
        bf16x8 f;
        #pragma unroll
        for (int i=0;i<8;i++) f[i] = (short)f2bf(wsrc[kh*32 + 8*g + i]);
        A[tt][kh] = f;
      }
    }
    const int j1 = 8*w + g, j2 = 8*w + 4 + g;
    const int jsel = (nl & 4) ? j2 : j1;
    const int bat  = b0 + (nl & 3);
    const bool active = (nl < 8);
    // pre stream for OWN cell (lanes >=8 alias lanes &7 -> L2 dedup)
    const unsigned short* pp = preh + (size_t)bat*256000 + jsel*4;
    uint2 P[4];
    #pragma unroll
    for (int s=0;s<4;s++) P[s] = *(const uint2*)(pp + (size_t)s*256);
    // LDS offsets (row = 64 shorts = 128B, 16B-block XOR swizzle by row&7)
    const int rdA = nl*64 + (g^sw)*8;
    const int rdB = nl*64 + ((4+g)^sw)*8;
    const int rw = nl & 3;                       // h-write row = batch-local
    const int wcol = rw*64 + ((w ^ rw)*8) + (jsel & 7);   // jsel>>3 == w
    unsigned short* lt = lstmT + ((size_t)bat*64 + jsel)*1000;
    const int srcl = (nl & 3) + 16*g;            // shfl source for D2
    float c = 0.f;
    unsigned ph[4];
    bf16x8 B0 = {}, B1 = {};
    __syncthreads();
    int buf = 0;
    for (int tb=0; tb<1000; tb+=8){
      #pragma unroll
      for (int u=0;u<8;u++){
        if (nl < 4){
          B0 = *(const bf16x8*)&hls[buf*1024 + rdA];
          B1 = *(const bf16x8*)&hls[buf*1024 + rdB];
        }
        const int slot = u & 3;
        f32x4 Cp = unpk4(P[slot]);
        int tp = tb + u + 4; if (tp > 999) tp = 999;
        P[slot] = *(const uint2*)(pp + (size_t)tp*256);
        const f32x4 z4 = {0.f,0.f,0.f,0.f};
        f32x4 D1 = __builtin_amdgcn_mfma_f32_16x16x32_bf16(A[0][0], B0, z4, 0,0,0);
        D1 = __builtin_amdgcn_mfma_f32_16x16x32_bf16(A[0][1], B1, D1, 0,0,0);
        f32x4 D2 = __builtin_amdgcn_mfma_f32_16x16x32_bf16(A[1][0], B0, z4, 0,0,0);
        D2 = __builtin_amdgcn_mfma_f32_16x16x32_bf16(A[1][1], B1, D2, 0,0,0);
        float d2s0 = __shfl(D2[0], srcl);
        float d2s1 = __shfl(D2[1], srcl);
        float d2s2 = __shfl(D2[2], srcl);
        float d2s3 = __shfl(D2[3], srcl);
        bool useD2 = (nl & 4);
        float g0 = (useD2 ? d2s0 : D1[0]) + Cp[0];
        float g1 = (useD2 ? d2s1 : D1[1]) + Cp[1];
        float g2 = (useD2 ? d2s2 : D1[2]) + Cp[2];
        float g3 = (useD2 ? d2s3 : D1[3]) + Cp[3];
        float iv = sig2(g0), fv = sig2(g1), gv = tanh2(g2), ov = sig2(g3);
        c = fv*c + iv*gv;
        float h = ov * tanh2(c);
        unsigned hb = f2bf(h);
        if (u & 1) ph[u>>1] |= hb << 16; else ph[u>>1] = hb;
        if (active) hls[(buf^1)*1024 + wcol] = (unsigned short)hb;
        asm volatile("s_waitcnt lgkmcnt(0)" ::: "memory");
        __builtin_amdgcn_s_barrier();
        asm volatile("" ::: "memory");
        buf ^= 1;
      }
      if (active) *(uint4*)(lt + tb) = make_uint4(ph[0], ph[1], ph[2], ph[3]);
    }
  } else {
    float* cw = (float*)shraw;        // 641*3 = 1923 floats
    for (int f = tid; f < 641*3; f += 512) cw[f] = conv_w[f];
    __syncthreads();
    int idx = (blockIdx.x - 8)*512 + tid;   // < 32256, guard 32000
    if (idx < 32000){
      int b = idx / 1000, n = idx - b*1000;
      float fcoef = fb[b*1000 + (n/100)];
      float dr = decay_p[0];
      const float dt = 1.0f/640.0f;
      float adec = 1.0f - dr*dt;
      float g = fcoef * sqrtf(dt);
      const float* nptr = noise + (size_t)idx * 640;
      float X=0.f, s0=0.f, s1=0.f, s2=0.f;
      for (int t0=0;t0<640;t0+=4){
        float4 nz = *(const float4*)&nptr[t0];
        float nv[4] = {nz.x, nz.y, nz.z, nz.w};
        #pragma unroll
        for (int u=0;u<4;u++){
          X = fmaf(adec, X, g*nv[u]);
          int t = t0 + u + 1;
          s0 = fmaf(cw[t*3+0], X, s0);
          s1 = fmaf(cw[t*3+1], X, s1);
          s2 = fmaf(cw[t*3+2], X, s2);
        }
      }
      S0[idx]=s0; S1[idx]=s1; S2[idx]=s2;
    }
  }
}

// ---------------- K4: qkv projection. lstm history is transposed bf16 [b][j][t].
__global__ __launch_bounds__(256) void k4_qkv(const unsigned short* __restrict__ lstmT,
  const float* __restrict__ w_in, const float* __restrict__ b_in,
  unsigned short* __restrict__ Qb, unsigned short* __restrict__ Kb, unsigned short* __restrict__ Vt)
{
  __shared__ __align__(16) float wl[192*64];   // 48KB
  __shared__ float bl[192];
  const int tid = threadIdx.x;
  for (int i=tid;i<3072;i+=256) ((float4*)wl)[i] = ((const float4*)w_in)[i];
  if (tid < 192) bl[tid] = b_in[tid];
  __syncthreads();
  const int rl = tid & 127, dh = tid >> 7;
  const int rn = blockIdx.x*128 + rl;         // never crosses a batch
  const int b = rn >> 10, n = rn & 1023;
  const bool valid = (n < 1000);
  const int nc = valid ? n : 999;
  float row[64];
  #pragma unroll
  for (int k=0;k<64;k++){
    unsigned v = lstmT[((size_t)b*64 + k)*1000 + nc];
    row[k] = valid ? __uint_as_float(v << 16) : 0.f;
  }
  for (int dc=0; dc<12; dc++){
    const int d0 = dh*96 + dc*8;
    float acc[8];
    #pragma unroll
    for (int u=0;u<8;u++) acc[u] = bl[d0+u];
    #pragma unroll
    for (int k=0;k<64;k+=4){
      float4 rv = *(const float4*)&row[k];
      #pragma unroll
      for (int u=0;u<8;u++){
        float4 wv = *(const float4*)&wl[(d0+u)*64 + k];
        acc[u]=fmaf(rv.x,wv.x,acc[u]); acc[u]=fmaf(rv.y,wv.y,acc[u]);
        acc[u]=fmaf(rv.z,wv.z,acc[u]); acc[u]=fmaf(rv.w,wv.w,acc[u]);
      }
    }
    unsigned short pk[8];
    #pragma unroll
    for (int u=0;u<8;u++) pk[u] = valid ? f2bf(acc[u]) : (unsigned short)0;
    if (d0 + 8 <= 64){
      *(bf16x8*)&Qb[(size_t)rn*64 + d0] = *(bf16x8*)pk;
    } else if (d0 + 8 <= 128){
      *(bf16x8*)&Kb[(size_t)rn*64 + (d0-64)] = *(bf16x8*)pk;
    } else {
      int dv = d0 - 128;
      #pragma unroll
      for (int u=0;u<8;u++) Vt[((size_t)b*64 + dv+u)*1024 + n] = pk[u];
    }
  }
}

// ---------------- K5: attention
__global__ __launch_bounds__(256) void k5_attn(
  const unsigned short* __restrict__ Qb, const unsigned short* __restrict__ Kb,
  const unsigned short* __restrict__ Vt,
  float* __restrict__ attn_w, float* __restrict__ ctx)
{
  const int b = blockIdx.x;
  const int qblk = blockIdx.y;
  const int wid = threadIdx.x >> 6;
  const int lane = threadIdx.x & 63;
  const int r = lane & 15, gq = lane >> 4;
  const int q0 = qblk*64 + wid*16;
  const int q = q0 + r;
  const bool gok = (gq < 2);
  const float scale = 0.25f;
  const f32x4 z4 = {0.f,0.f,0.f,0.f};

  bf16x8 qf[4];
  #pragma unroll
  for (int h=0; h<4; h++){
    bf16x8 f = {};
    if (gok) f = *(const bf16x8*)&Qb[(((size_t)b*1024)+q)*64 + h*16 + 8*gq];
    qf[h] = f;
  }
  float sinv[4];
  #pragma unroll
  for (int h=0; h<4; h++){
    float es = 0.f;
    for (int kk=0; kk<63; kk++){
      bf16x8 kf = {};
      if (gok) kf = *(const bf16x8*)&Kb[(((size_t)b*1024)+(kk*16+r))*64 + h*16 + 8*gq];
      f32x4 d = __builtin_amdgcn_mfma_f32_16x16x32_bf16(kf, qf[h], z4, 0,0,0);
      float e0=__expf(d[0]*scale), e1=__expf(d[1]*scale), e2=__expf(d[2]*scale), e3=__expf(d[3]*scale);
      if (kk == 62 && !gok){ e0=0;e1=0;e2=0;e3=0; }
      es += (e0+e1)+(e2+e3);
    }
    es += __shfl_xor(es, 16);
    es += __shfl_xor(es, 32);
    sinv[h] = 1.0f / es;
  }
  f32x4 cacc[4] = {};
  float* awrow = attn_w + (size_t)b*1000000;
  for (int kk=0; kk<63; kk++){
    f32x4 aacc = z4;
    #pragma unroll
    for (int h=0; h<4; h++){
      bf16x8 kf = {};
      if (gok) kf = *(const bf16x8*)&Kb[(((size_t)b*1024)+(kk*16+r))*64 + h*16 + 8*gq];
      f32x4 d = __builtin_amdgcn_mfma_f32_16x16x32_bf16(kf, qf[h], z4, 0,0,0);
      float p0=__expf(d[0]*scale)*sinv[h], p1=__expf(d[1]*scale)*sinv[h];
      float p2=__expf(d[2]*scale)*sinv[h], p3=__expf(d[3]*scale)*sinv[h];
      if (kk == 62 && !gok){ p0=0;p1=0;p2=0;p3=0; }
      aacc[0] += 0.25f*p0; aacc[1] += 0.25f*p1; aacc[2] += 0.25f*p2; aacc[3] += 0.25f*p3;
      unsigned p01 = (unsigned)f2bf(p0) | ((unsigned)f2bf(p1) << 16);
      unsigned p23 = (unsigned)f2bf(p2) | ((unsigned)f2bf(p3) << 16);
      int slo = (r + 32*gq) & 63;
      int shi = (slo + 16) & 63;
      int b0 = __shfl((int)p01, slo), b1 = __shfl((int)p23, slo);
      int b2 = __shfl((int)p01, shi), b3 = __shfl((int)p23, shi);
      union { int i[4]; bf16x8 v; } pu;
      pu.i[0]=b0; pu.i[1]=b1; pu.i[2]=b2; pu.i[3]=b3;
      bf16x8 pfrag = pu.v;
      if (!gok) pfrag = (bf16x8){};
      bf16x8 vf = {};
      if (gok) vf = *(const bf16x8*)&Vt[(((size_t)b*64) + h*16 + r)*1024 + kk*16 + 8*gq];
      cacc[h] = __builtin_amdgcn_mfma_f32_16x16x32_bf16(vf, pfrag, cacc[h], 0,0,0);
    }
    int kbase = kk*16 + 4*gq;
    if (q < 1000 && !(kk==62 && !gok)){
      *(f32x4*)&awrow[(size_t)q*1000 + kbase] = aacc;
    }
  }
  if (q < 1000){
    #pragma unroll
    for (int h=0; h<4; h++){
      *(f32x4*)&ctx[(((size_t)b*1024)+q)*64 + h*16 + 4*gq] = cacc[h];
    }
  }
}

// ---------------- K6: enn = relu((sum_n ctx)@w_out.T/1000 + b_out) @ W_fix.T
__global__ __launch_bounds__(256) void k6_enn(const float* __restrict__ ctx,
  const float* __restrict__ w_out, const float* __restrict__ b_out,
  const float* __restrict__ W_fix, float* __restrict__ enn_out)
{
  __shared__ __align__(16) float csum[64];
  __shared__ __align__(16) float epre[64];
  __shared__ float part[256];
  int b = blockIdx.x, t = threadIdx.x;
  int d = t & 63, sg = t >> 6;
  float s0=0,s1=0;
  int nbeg = sg*250, nend = nbeg+250;
  for (int n=nbeg; n<nend; n+=2){
    s0 += ctx[(((size_t)b*1024)+n)*64 + d];
    s1 += ctx[(((size_t)b*1024)+n+1)*64 + d];
  }
  part[t] = s0+s1;
  __syncthreads();
  if (t < 64) csum[t] = part[t] + part[64+t] + part[128+t] + part[192+t];
  __syncthreads();
  if (t < 64){
    const float* wr = w_out + t*64;
    float a = 0;
    #pragma unroll
    for (int k=0;k<64;k++) a = fmaf(csum[k], wr[k], a);
    epre[t] = fmaxf(a*(1.0f/1000.0f) + b_out[t], 0.0f);
  }
  __syncthreads();
  for (int m = t; m < 1024; m += 256){
    const float* fr = W_fix + m*64;
    float a = 0;
    #pragma unroll
    for (int k=0;k<64;k+=4){
      float4 e4 = *(const float4*)&epre[k];
      float4 f4 = *(const float4*)&fr[k];
      a=fmaf(e4.x,f4.x,a); a=fmaf(e4.y,f4.y,a); a=fmaf(e4.z,f4.z,a); a=fmaf(e4.w,f4.w,a);
    }
    enn_out[b*1024 + m] = a;
  }
}

// ---------------- K7: agg = shifted sums of S0/S1/S2 + conv_b
__global__ __launch_bounds__(256) void k7_agg(const float* __restrict__ S0, const float* __restrict__ S1,
  const float* __restrict__ S2, const float* __restrict__ conv_b, float* __restrict__ agg)
{
  int i = blockIdx.x*256 + threadIdx.x;
  if (i >= 32000) return;
  int n = i % 1000;
  float v = S1[i] + conv_b[0];
  if (n > 0)   v += S0[i-1];
  if (n < 999) v += S2[i+1];
  agg[i] = v;
}

// ---------------- K8: bicep = agg@W_bout.T + b_bout
__global__ __launch_bounds__(64) void k8_bicep(const float* __restrict__ agg,
  const float* __restrict__ W_bout, const float* __restrict__ b_bout, float* __restrict__ bicep)
{
  int gt = blockIdx.x*64 + threadIdx.x;
  int bb = gt & 31, m = gt >> 5;
  const float* wr = W_bout + (size_t)m*1000;
  const float* ar = agg + bb*1000;
  float a = 0;
  for (int n=0;n<1000;n+=4){
    float4 w4 = *(const float4*)&wr[n];
    float4 a4 = *(const float4*)&ar[n];
    a=fmaf(w4.x,a4.x,a); a=fmaf(w4.y,a4.y,a); a=fmaf(w4.z,a4.z,a); a=fmaf(w4.w,a4.w,a);
  }
  bicep[bb*1024 + m] = a + b_bout[m];
}

// ---------------- K9: fused = [enn,bicep]@W_fuse.T + b_fuse
__global__ __launch_bounds__(64) void k9_fuse(const float* __restrict__ enn, const float* __restrict__ bic,
  const float* __restrict__ W_fuse, const float* __restrict__ b_fuse, float* __restrict__ fused)
{
  int gt = blockIdx.x*64 + threadIdx.x;
  int bb = gt & 31, m = gt >> 5;
  const float* er = enn + bb*1024;
  const float* br = bic + bb*1024;
  const float* wr = W_fuse + (size_t)m*2048;
  float a = 0;
  for (int jj=0;jj<1024;jj+=4){
    float4 e4 = *(const float4*)&er[jj];
    float4 w4 = *(const float4*)&wr[jj];
    a=fmaf(e4.x,w4.x,a); a=fmaf(e4.y,w4.y,a); a=fmaf(e4.z,w4.z,a); a=fmaf(e4.w,w4.w,a);
  }
  for (int jj=0;jj<1024;jj+=4){
    float4 b4 = *(const float4*)&br[jj];
    float4 w4 = *(const float4*)&wr[1024+jj];
    a=fmaf(b4.x,w4.x,a); a=fmaf(b4.y,w4.y,a); a=fmaf(b4.z,w4.z,a); a=fmaf(b4.w,w4.w,a);
  }
  fused[bb*1024 + m] = a + b_fuse[m];
}

// ---------------- K10: output = fused@W_proj.T + b_proj
__global__ __launch_bounds__(64) void k10_proj(const float* __restrict__ fused,
  const float* __restrict__ W_proj, const float* __restrict__ b_proj, float* __restrict__ outp)
{
  int gt = blockIdx.x*64 + threadIdx.x;
  int bb = gt & 31, m = gt >> 5;
  const float* fr = fused + bb*1024;
  const float* wr = W_proj + (size_t)m*1024;
  float a = 0;
  for (int jj=0;jj<1024;jj+=4){
    float4 f4 = *(const float4*)&fr[jj];
    float4 w4 = *(const float4*)&wr[jj];
    a=fmaf(f4.x,w4.x,a); a=fmaf(f4.y,w4.y,a); a=fmaf(f4.z,w4.z,a); a=fmaf(f4.w,w4.w,a);
  }
  outp[bb*1024 + m] = a + b_proj[m];
}

extern "C" void kernel_launch(void* const* d_in, const int* in_sizes, int n_in,
                              void* d_out, int out_size, void* d_ws, size_t ws_size,
                              hipStream_t stream)
{
  const float* x       = (const float*)d_in[0];
  const float* noise   = (const float*)d_in[1];
  const float* W_emb   = (const float*)d_in[2];
  const float* b_emb   = (const float*)d_in[3];
  const float* w_ih    = (const float*)d_in[4];
  const float* w_hh    = (const float*)d_in[5];
  const float* b_ih    = (const float*)d_in[6];
  const float* b_hh    = (const float*)d_in[7];
  const float* w_in    = (const float*)d_in[8];
  const float* b_in    = (const float*)d_in[9];
  const float* w_out   = (const float*)d_in[10];
  const float* b_out   = (const float*)d_in[11];
  const float* W_fix   = (const float*)d_in[12];
  const float* W_inp   = (const float*)d_in[13];
  const float* b_inp   = (const float*)d_in[14];
  const float* conv_w  = (const float*)d_in[15];
  const float* conv_b  = (const float*)d_in[16];
  const float* W_bout  = (const float*)d_in[17];
  const float* b_bout  = (const float*)d_in[18];
  const float* decay   = (const float*)d_in[19];
  const float* W_fuse  = (const float*)d_in[20];
  const float* b_fuse  = (const float*)d_in[21];
  const float* W_proj  = (const float*)d_in[22];
  const float* b_proj  = (const float*)d_in[23];

  float* out       = (float*)d_out;
  float* enn_out   = out + 32768;
  float* bicep_out = out + 65536;
  float* attn_out  = out + 98304;

  float* ws    = (float*)d_ws;
  float* fb    = ws;                    // 32000
  float* ns    = ws + 32000;            // 2,048,000
  unsigned short* preh  = (unsigned short*)(ws + 2080000);   // 8,192,000 u16
  unsigned short* lstmT = (unsigned short*)(ws + 10272000);  // 2,048,000 u16
  float* ctx   = ws + 12320000;         // 2,097,152
  float* S0    = ws + 14417152;         // 32000
  float* S1    = ws + 14449152;
  float* S2    = ws + 14481152;
  float* agg   = ws + 14513152;
  float* fused = ws + 14545152;         // 32768
  unsigned short* Qb = (unsigned short*)(ws + 14577920);  // 2,097,152 u16 each
  unsigned short* Kb = Qb + 2097152;
  unsigned short* Vt = Kb + 2097152;

  k1_emb<<<4063, 256, 0, stream>>>(x, W_emb, b_emb, W_inp, b_inp, ns, fb);
  k2_pre<<<500, 256, 0, stream>>>(ns, w_ih, b_ih, b_hh, preh);
  k3_lstm_sde<<<71, 512, 0, stream>>>(preh, lstmT, w_hh, noise, fb, conv_w, decay, S0, S1, S2);
  k4_qkv<<<256, 256, 0, stream>>>(lstmT, w_in, b_in, Qb, Kb, Vt);
  k5_attn<<<dim3(32,16), 256, 0, stream>>>(Qb, Kb, Vt, attn_out, ctx);
  k6_enn<<<32, 256, 0, stream>>>(ctx, w_out, b_out, W_fix, enn_out);
  k7_agg<<<126, 256, 0, stream>>>(S0, S1, S2, conv_b, agg);
  k8_bicep<<<512, 64, 0, stream>>>(agg, W_bout, b_bout, bicep_out);
  k9_fuse<<<512, 64, 0, stream>>>(enn_out, bicep_out, W_fuse, b_fuse, fused);
  k10_proj<<<512, 64, 0, stream>>>(fused, W_proj, b_proj, out);
}

// Round 6
// 931.939 us; speedup vs baseline: 2.0719x; 1.0138x over previous
//
#include <hip/hip_runtime.h>
#include <hip/hip_bf16.h>
#include <math.h>

#define BATCH 32
#define NNEUR 1000
#define NSTATE 64
#define INDIM 1024
#define HID 1024

typedef short bf16x8 __attribute__((ext_vector_type(8)));
typedef float f32x4 __attribute__((ext_vector_type(4)));

__device__ __forceinline__ float sigmoidf_(float x){ return 1.0f/(1.0f + __expf(-x)); }
__device__ __forceinline__ unsigned short f2bf(float x){
  unsigned u = __float_as_uint(x);
  unsigned r = (u + 0x7FFFu + ((u>>16)&1u)) >> 16;
  return (unsigned short)r;
}
// saturation-safe fast sigmoid/tanh via v_exp_f32 (exp2) + v_rcp_f32.
__device__ __forceinline__ float sig2(float x){
  return __builtin_amdgcn_rcpf(1.0f + __builtin_amdgcn_exp2f(x * -1.44269504f));
}
__device__ __forceinline__ float tanh2(float x){
  return 1.0f - 2.0f*__builtin_amdgcn_rcpf(1.0f + __builtin_amdgcn_exp2f(x * 2.88539008f));
}
__device__ __forceinline__ f32x4 unpk4(uint2 p){
  f32x4 r;
  r[0] = __uint_as_float(p.x << 16);
  r[1] = __uint_as_float(p.x & 0xffff0000u);
  r[2] = __uint_as_float(p.y << 16);
  r[3] = __uint_as_float(p.y & 0xffff0000u);
  return r;
}

// ---------------- K1: ns = x@W_emb.T + b_emb ; fb = sigmoid(x@W_inproj.T + b_inproj)
// 1016 blocks x 64 j-rows. Thread = (jt 0..15, seg 0..15) owns 4 j-rows; each LDS
// xv read feeds 16 FMAs (VALU-bound, not LDS-bound).
__global__ __launch_bounds__(256) void k1_emb(const float* __restrict__ x,
    const float* __restrict__ W_emb, const float* __restrict__ b_emb,
    const float* __restrict__ W_inp, const float* __restrict__ b_inp,
    float* __restrict__ ns, float* __restrict__ fb)
{
  __shared__ __align__(16) float xl[BATCH][256];
  __shared__ float red[64][33];
  const int tid = threadIdx.x;
  const int jt = tid >> 4;    // 0..15
  const int seg = tid & 15;   // 0..15
  const int j0 = blockIdx.x * 64;
  const float* wr_[4];
  #pragma unroll
  for (int jj=0;jj<4;jj++){
    int j = j0 + jt*4 + jj;
    if (j < 64000) wr_[jj] = W_emb + (size_t)j * INDIM;
    else { int t2 = j - 64000; if (t2 > 999) t2 = 999; wr_[jj] = W_inp + (size_t)t2 * INDIM; }
  }
  float acc[4][32];
  #pragma unroll
  for (int jj=0;jj<4;jj++)
    #pragma unroll
    for (int b=0;b<32;b++) acc[jj][b]=0.f;
  for (int c=0;c<4;c++){
    __syncthreads();
    for (int f = tid; f < 2048; f += 256){
      int b = f >> 6; int col = (f & 63) << 2;
      *(float4*)&xl[b][col] = *(const float4*)&x[b*INDIM + c*256 + col];
    }
    __syncthreads();
    #pragma unroll
    for (int ii=0; ii<4; ii++){
      float4 wv[4];
      #pragma unroll
      for (int jj=0;jj<4;jj++) wv[jj] = *(const float4*)&wr_[jj][c*256 + ii*64 + seg*4];
      #pragma unroll
      for (int b=0;b<32;b++){
        float4 xv = *(const float4*)&xl[b][ii*64 + seg*4];
        #pragma unroll
        for (int jj=0;jj<4;jj++){
          acc[jj][b] = fmaf(wv[jj].x, xv.x, acc[jj][b]);
          acc[jj][b] = fmaf(wv[jj].y, xv.y, acc[jj][b]);
          acc[jj][b] = fmaf(wv[jj].z, xv.z, acc[jj][b]);
          acc[jj][b] = fmaf(wv[jj].w, xv.w, acc[jj][b]);
        }
      }
    }
  }
  #pragma unroll
  for (int jj=0;jj<4;jj++){
    #pragma unroll
    for (int b=0;b<32;b++){
      float v = acc[jj][b];
      v += __shfl_xor(v, 1);
      v += __shfl_xor(v, 2);
      v += __shfl_xor(v, 4);
      v += __shfl_xor(v, 8);
      if (seg == 0) red[jt*4+jj][b] = v;
    }
  }
  __syncthreads();
  #pragma unroll
  for (int it=0; it<8; it++){
    int idx = it*256 + tid;       // 0..2047
    int b = idx >> 6, jl = idx & 63;
    int jg = j0 + jl;
    float v = red[jl][b];
    if (jg < 64000){
      ns[(size_t)b*64000 + jg] = v + b_emb[jg];
    } else if (jg < 65000){
      fb[b*1000 + (jg-64000)] = sigmoidf_(v + b_inp[jg-64000]);
    }
  }
}

// ---------------- K2: preh[rn][perm(j)] = bf16( ns[rn,:]@w_ih[j,:] + b_ih[j] + b_hh[j] )
__global__ __launch_bounds__(256) void k2_pre(const float* __restrict__ ns,
   const float* __restrict__ w_ih, const float* __restrict__ b_ih, const float* __restrict__ b_hh,
   unsigned short* __restrict__ preh)
{
  __shared__ __align__(16) float nsl[64*64];   // 16KB
  const int tid = threadIdx.x;
  const int j = tid;                 // original gate-row 0..255 (gate = j>>6, jl = j&63)
  const int rn0 = blockIdx.x * 64;
  const int pcol = (j & 63)*4 + (j >> 6);
  float wreg[64];
  const float* wr = w_ih + j*64;
  #pragma unroll
  for (int k=0;k<64;k+=4){
    float4 v = *(const float4*)&wr[k];
    wreg[k]=v.x; wreg[k+1]=v.y; wreg[k+2]=v.z; wreg[k+3]=v.w;
  }
  float bias = b_ih[j] + b_hh[j];
  const float4* src = (const float4*)(ns + (size_t)rn0*64);
  for (int i=tid; i<64*16; i+=256) ((float4*)nsl)[i] = src[i];
  __syncthreads();
  for (int r=0;r<64;r++){
    float a0=0,a1=0,a2=0,a3=0;
    #pragma unroll
    for (int k=0;k<64;k+=4){
      float4 nv = *(const float4*)&nsl[r*64+k];
      a0=fmaf(nv.x,wreg[k],a0);   a1=fmaf(nv.y,wreg[k+1],a1);
      a2=fmaf(nv.z,wreg[k+2],a2); a3=fmaf(nv.w,wreg[k+3],a3);
    }
    preh[(size_t)(rn0+r)*256 + pcol] = f2bf((a0+a1)+(a2+a3) + bias);
  }
}

// ---------------- K3: blocks 0..7 = MFMA LSTM (256 thr, 4 waves, 4 batches);
//                     blocks 8..132 = SDE+conv (256 thr)
// "1 cell per lane": wave w computes tiles rt=4w..4w+3 (j=16w..16w+15). LDS h =
// [2][4 rows][80] bf16 (row=batch, XOR block swizzle); B-cols replicate the 4
// batches 4x. Lane (nl,g) consumes tile nl>>2 via cndmask -> owns cell
// (batch=nl&3, j=16w+4*(nl>>2)+g). Pre-adds ride the MFMA C operand.
__global__ __launch_bounds__(256) void k3_lstm_sde(
  const unsigned short* __restrict__ preh, unsigned short* __restrict__ lstmT,
  const float* __restrict__ w_hh,
  const float* __restrict__ noise, const float* __restrict__ fb,
  const float* __restrict__ conv_w, const float* __restrict__ decay_p,
  float* __restrict__ S0, float* __restrict__ S1, float* __restrict__ S2)
{
  __shared__ __align__(16) unsigned char shraw[8192];
  const int tid = threadIdx.x;
  if (blockIdx.x < 8){
    unsigned short* hls = (unsigned short*)shraw;   // [2][4][80] bf16 = 640 shorts
    const int b0 = blockIdx.x * 4;
    const int w = tid >> 6;          // wave 0..3
    const int lane = tid & 63;
    const int nl = lane & 15;
    const int g  = lane >> 4;        // 0..3
    const int r  = nl & 3;           // batch-local row
    for (int i = tid; i < 640; i += 256) hls[i] = 0;
    // A-frags for tiles rt=4w+tt
    bf16x8 A[4][2];
    #pragma unroll
    for (int tt=0; tt<4; tt++){
      const int rt = 4*w + tt;
      const float* wsrc = w_hh + (size_t)((nl&3)*64 + 4*rt + (nl>>2))*64;
      #pragma unroll
      for (int kh=0; kh<2; kh++){
        bf16x8 f;
        #pragma unroll
        for (int i=0;i<8;i++) f[i] = (short)f2bf(wsrc[kh*32 + 8*g + i]);
        A[tt][kh] = f;
      }
    }
    const int jg = 16*w + 4*(nl>>2) + g;    // this lane's cell j (global 0..63)
    const int bat = b0 + r;
    const unsigned short* pp = preh + (size_t)bat*256000 + jg*4;
    uint2 P[4];
    #pragma unroll
    for (int s=0;s<4;s++) P[s] = *(const uint2*)(pp + (size_t)s*256);
    // LDS short offsets: row r = 80 shorts (160B); 16B block XOR-swizzled by r
    const int rdA = r*80 + (g ^ r)*8;            // B0: logical k-block g
    // rdB = rdA + 32 (block 4+g)
    const int wr = r*80 + ((jg>>3) ^ r)*8 + (jg & 7);
    unsigned short* lt = lstmT + ((size_t)bat*64 + jg)*1000;
    const bool s1 = (nl & 4) != 0, s2 = (nl & 8) != 0;
    float c = 0.f;
    unsigned ph[4];
    __syncthreads();
    int buf = 0;
    for (int tb=0; tb<1000; tb+=8){
      #pragma unroll
      for (int u=0;u<8;u++){
        bf16x8 B0 = *(const bf16x8*)&hls[buf*320 + rdA];
        bf16x8 B1 = *(const bf16x8*)&hls[buf*320 + rdA + 32];
        const int slot = u & 3;
        f32x4 Cp = unpk4(P[slot]);
        int tp = tb + u + 4; if (tp > 999) tp = 999;
        P[slot] = *(const uint2*)(pp + (size_t)tp*256);
        f32x4 D0 = __builtin_amdgcn_mfma_f32_16x16x32_bf16(A[0][0], B0, Cp, 0,0,0);
        D0 = __builtin_amdgcn_mfma_f32_16x16x32_bf16(A[0][1], B1, D0, 0,0,0);
        f32x4 D1 = __builtin_amdgcn_mfma_f32_16x16x32_bf16(A[1][0], B0, Cp, 0,0,0);
        D1 = __builtin_amdgcn_mfma_f32_16x16x32_bf16(A[1][1], B1, D1, 0,0,0);
        f32x4 D2 = __builtin_amdgcn_mfma_f32_16x16x32_bf16(A[2][0], B0, Cp, 0,0,0);
        D2 = __builtin_amdgcn_mfma_f32_16x16x32_bf16(A[2][1], B1, D2, 0,0,0);
        f32x4 D3 = __builtin_amdgcn_mfma_f32_16x16x32_bf16(A[3][0], B0, Cp, 0,0,0);
        D3 = __builtin_amdgcn_mfma_f32_16x16x32_bf16(A[3][1], B1, D3, 0,0,0);
        // select own tile (nl>>2) via cndmask tree
        float g0 = s2 ? (s1 ? D3[0] : D2[0]) : (s1 ? D1[0] : D0[0]);
        float g1 = s2 ? (s1 ? D3[1] : D2[1]) : (s1 ? D1[1] : D0[1]);
        float g2 = s2 ? (s1 ? D3[2] : D2[2]) : (s1 ? D1[2] : D0[2]);
        float g3 = s2 ? (s1 ? D3[3] : D2[3]) : (s1 ? D1[3] : D0[3]);
        float iv = sig2(g0), fv = sig2(g1), gv = tanh2(g2), ov = sig2(g3);
        c = fv*c + iv*gv;
        float h = ov * tanh2(c);
        unsigned hb = f2bf(h);
        if (u & 1) ph[u>>1] |= hb << 16; else ph[u>>1] = hb;
        hls[(buf^1)*320 + wr] = (unsigned short)hb;
        asm volatile("s_waitcnt lgkmcnt(0)" ::: "memory");
        __builtin_amdgcn_s_barrier();
        asm volatile("" ::: "memory");
        buf ^= 1;
      }
      *(uint4*)(lt + tb) = make_uint4(ph[0], ph[1], ph[2], ph[3]);
    }
  } else {
    float* cw = (float*)shraw;        // 641*3 = 1923 floats
    for (int f = tid; f < 641*3; f += 256) cw[f] = conv_w[f];
    __syncthreads();
    int idx = (blockIdx.x - 8)*256 + tid;   // < 32000
    if (idx < 32000){
      int b = idx / 1000, n = idx - b*1000;
      float fcoef = fb[b*1000 + (n/100)];
      float dr = decay_p[0];
      const float dt = 1.0f/640.0f;
      float adec = 1.0f - dr*dt;
      float g = fcoef * sqrtf(dt);
      const float* nptr = noise + (size_t)idx * 640;
      float X=0.f, s0=0.f, s1=0.f, s2=0.f;
      for (int t0=0;t0<640;t0+=4){
        float4 nz = *(const float4*)&nptr[t0];
        float nv[4] = {nz.x, nz.y, nz.z, nz.w};
        #pragma unroll
        for (int u=0;u<4;u++){
          X = fmaf(adec, X, g*nv[u]);
          int t = t0 + u + 1;
          s0 = fmaf(cw[t*3+0], X, s0);
          s1 = fmaf(cw[t*3+1], X, s1);
          s2 = fmaf(cw[t*3+2], X, s2);
        }
      }
      S0[idx]=s0; S1[idx]=s1; S2[idx]=s2;
    }
  }
}

// ---------------- K4: qkv projection. lstm history is transposed bf16 [b][j][t].
__global__ __launch_bounds__(256) void k4_qkv(const unsigned short* __restrict__ lstmT,
  const float* __restrict__ w_in, const float* __restrict__ b_in,
  unsigned short* __restrict__ Qb, unsigned short* __restrict__ Kb, unsigned short* __restrict__ Vt)
{
  __shared__ __align__(16) float wl[192*64];   // 48KB
  __shared__ float bl[192];
  const int tid = threadIdx.x;
  for (int i=tid;i<3072;i+=256) ((float4*)wl)[i] = ((const float4*)w_in)[i];
  if (tid < 192) bl[tid] = b_in[tid];
  __syncthreads();
  const int rl = tid & 127, dh = tid >> 7;
  const int rn = blockIdx.x*128 + rl;         // never crosses a batch
  const int b = rn >> 10, n = rn & 1023;
  const bool valid = (n < 1000);
  const int nc = valid ? n : 999;
  float row[64];
  #pragma unroll
  for (int k=0;k<64;k++){
    unsigned v = lstmT[((size_t)b*64 + k)*1000 + nc];
    row[k] = valid ? __uint_as_float(v << 16) : 0.f;
  }
  for (int dc=0; dc<12; dc++){
    const int d0 = dh*96 + dc*8;
    float acc[8];
    #pragma unroll
    for (int u=0;u<8;u++) acc[u] = bl[d0+u];
    #pragma unroll
    for (int k=0;k<64;k+=4){
      float4 rv = *(const float4*)&row[k];
      #pragma unroll
      for (int u=0;u<8;u++){
        float4 wv = *(const float4*)&wl[(d0+u)*64 + k];
        acc[u]=fmaf(rv.x,wv.x,acc[u]); acc[u]=fmaf(rv.y,wv.y,acc[u]);
        acc[u]=fmaf(rv.z,wv.z,acc[u]); acc[u]=fmaf(rv.w,wv.w,acc[u]);
      }
    }
    unsigned short pk[8];
    #pragma unroll
    for (int u=0;u<8;u++) pk[u] = valid ? f2bf(acc[u]) : (unsigned short)0;
    if (d0 + 8 <= 64){
      *(bf16x8*)&Qb[(size_t)rn*64 + d0] = *(bf16x8*)pk;
    } else if (d0 + 8 <= 128){
      *(bf16x8*)&Kb[(size_t)rn*64 + (d0-64)] = *(bf16x8*)pk;
    } else {
      int dv = d0 - 128;
      #pragma unroll
      for (int u=0;u<8;u++) Vt[((size_t)b*64 + dv+u)*1024 + n] = pk[u];
    }
  }
}

// ---------------- K5: attention
__global__ __launch_bounds__(256) void k5_attn(
  const unsigned short* __restrict__ Qb, const unsigned short* __restrict__ Kb,
  const unsigned short* __restrict__ Vt,
  float* __restrict__ attn_w, float* __restrict__ ctx)
{
  const int b = blockIdx.x;
  const int qblk = blockIdx.y;
  const int wid = threadIdx.x >> 6;
  const int lane = threadIdx.x & 63;
  const int r = lane & 15, gq = lane >> 4;
  const int q0 = qblk*64 + wid*16;
  const int q = q0 + r;
  const bool gok = (gq < 2);
  const float scale = 0.25f;
  const f32x4 z4 = {0.f,0.f,0.f,0.f};

  bf16x8 qf[4];
  #pragma unroll
  for (int h=0; h<4; h++){
    bf16x8 f = {};
    if (gok) f = *(const bf16x8*)&Qb[(((size_t)b*1024)+q)*64 + h*16 + 8*gq];
    qf[h] = f;
  }
  float sinv[4];
  #pragma unroll
  for (int h=0; h<4; h++){
    float es = 0.f;
    for (int kk=0; kk<63; kk++){
      bf16x8 kf = {};
      if (gok) kf = *(const bf16x8*)&Kb[(((size_t)b*1024)+(kk*16+r))*64 + h*16 + 8*gq];
      f32x4 d = __builtin_amdgcn_mfma_f32_16x16x32_bf16(kf, qf[h], z4, 0,0,0);
      float e0=__expf(d[0]*scale), e1=__expf(d[1]*scale), e2=__expf(d[2]*scale), e3=__expf(d[3]*scale);
      if (kk == 62 && !gok){ e0=0;e1=0;e2=0;e3=0; }
      es += (e0+e1)+(e2+e3);
    }
    es += __shfl_xor(es, 16);
    es += __shfl_xor(es, 32);
    sinv[h] = 1.0f / es;
  }
  f32x4 cacc[4] = {};
  float* awrow = attn_w + (size_t)b*1000000;
  for (int kk=0; kk<63; kk++){
    f32x4 aacc = z4;
    #pragma unroll
    for (int h=0; h<4; h++){
      bf16x8 kf = {};
      if (gok) kf = *(const bf16x8*)&Kb[(((size_t)b*1024)+(kk*16+r))*64 + h*16 + 8*gq];
      f32x4 d = __builtin_amdgcn_mfma_f32_16x16x32_bf16(kf, qf[h], z4, 0,0,0);
      float p0=__expf(d[0]*scale)*sinv[h], p1=__expf(d[1]*scale)*sinv[h];
      float p2=__expf(d[2]*scale)*sinv[h], p3=__expf(d[3]*scale)*sinv[h];
      if (kk == 62 && !gok){ p0=0;p1=0;p2=0;p3=0; }
      aacc[0] += 0.25f*p0; aacc[1] += 0.25f*p1; aacc[2] += 0.25f*p2; aacc[3] += 0.25f*p3;
      unsigned p01 = (unsigned)f2bf(p0) | ((unsigned)f2bf(p1) << 16);
      unsigned p23 = (unsigned)f2bf(p2) | ((unsigned)f2bf(p3) << 16);
      int slo = (r + 32*gq) & 63;
      int shi = (slo + 16) & 63;
      int b0 = __shfl((int)p01, slo), b1 = __shfl((int)p23, slo);
      int b2 = __shfl((int)p01, shi), b3 = __shfl((int)p23, shi);
      union { int i[4]; bf16x8 v; } pu;
      pu.i[0]=b0; pu.i[1]=b1; pu.i[2]=b2; pu.i[3]=b3;
      bf16x8 pfrag = pu.v;
      if (!gok) pfrag = (bf16x8){};
      bf16x8 vf = {};
      if (gok) vf = *(const bf16x8*)&Vt[(((size_t)b*64) + h*16 + r)*1024 + kk*16 + 8*gq];
      cacc[h] = __builtin_amdgcn_mfma_f32_16x16x32_bf16(vf, pfrag, cacc[h], 0,0,0);
    }
    int kbase = kk*16 + 4*gq;
    if (q < 1000 && !(kk==62 && !gok)){
      *(f32x4*)&awrow[(size_t)q*1000 + kbase] = aacc;
    }
  }
  if (q < 1000){
    #pragma unroll
    for (int h=0; h<4; h++){
      *(f32x4*)&ctx[(((size_t)b*1024)+q)*64 + h*16 + 4*gq] = cacc[h];
    }
  }
}

// ---------------- K6: enn = relu((sum_n ctx)@w_out.T/1000 + b_out) @ W_fix.T
__global__ __launch_bounds__(256) void k6_enn(const float* __restrict__ ctx,
  const float* __restrict__ w_out, const float* __restrict__ b_out,
  const float* __restrict__ W_fix, float* __restrict__ enn_out)
{
  __shared__ __align__(16) float csum[64];
  __shared__ __align__(16) float epre[64];
  __shared__ float part[256];
  int b = blockIdx.x, t = threadIdx.x;
  int d = t & 63, sg = t >> 6;
  float s0=0,s1=0;
  int nbeg = sg*250, nend = nbeg+250;
  for (int n=nbeg; n<nend; n+=2){
    s0 += ctx[(((size_t)b*1024)+n)*64 + d];
    s1 += ctx[(((size_t)b*1024)+n+1)*64 + d];
  }
  part[t] = s0+s1;
  __syncthreads();
  if (t < 64) csum[t] = part[t] + part[64+t] + part[128+t] + part[192+t];
  __syncthreads();
  if (t < 64){
    const float* wr = w_out + t*64;
    float a = 0;
    #pragma unroll
    for (int k=0;k<64;k++) a = fmaf(csum[k], wr[k], a);
    epre[t] = fmaxf(a*(1.0f/1000.0f) + b_out[t], 0.0f);
  }
  __syncthreads();
  for (int m = t; m < 1024; m += 256){
    const float* fr = W_fix + m*64;
    float a = 0;
    #pragma unroll
    for (int k=0;k<64;k+=4){
      float4 e4 = *(const float4*)&epre[k];
      float4 f4 = *(const float4*)&fr[k];
      a=fmaf(e4.x,f4.x,a); a=fmaf(e4.y,f4.y,a); a=fmaf(e4.z,f4.z,a); a=fmaf(e4.w,f4.w,a);
    }
    enn_out[b*1024 + m] = a;
  }
}

// ---------------- K7: agg = shifted sums of S0/S1/S2 + conv_b
__global__ __launch_bounds__(256) void k7_agg(const float* __restrict__ S0, const float* __restrict__ S1,
  const float* __restrict__ S2, const float* __restrict__ conv_b, float* __restrict__ agg)
{
  int i = blockIdx.x*256 + threadIdx.x;
  if (i >= 32000) return;
  int n = i % 1000;
  float v = S1[i] + conv_b[0];
  if (n > 0)   v += S0[i-1];
  if (n < 999) v += S2[i+1];
  agg[i] = v;
}

// ---------------- K8: bicep = agg@W_bout.T + b_bout
__global__ __launch_bounds__(64) void k8_bicep(const float* __restrict__ agg,
  const float* __restrict__ W_bout, const float* __restrict__ b_bout, float* __restrict__ bicep)
{
  int gt = blockIdx.x*64 + threadIdx.x;
  int bb = gt & 31, m = gt >> 5;
  const float* wr = W_bout + (size_t)m*1000;
  const float* ar = agg + bb*1000;
  float a = 0;
  for (int n=0;n<1000;n+=4){
    float4 w4 = *(const float4*)&wr[n];
    float4 a4 = *(const float4*)&ar[n];
    a=fmaf(w4.x,a4.x,a); a=fmaf(w4.y,a4.y,a); a=fmaf(w4.z,a4.z,a); a=fmaf(w4.w,a4.w,a);
  }
  bicep[bb*1024 + m] = a + b_bout[m];
}

// ---------------- K9: fused = [enn,bicep]@W_fuse.T + b_fuse
__global__ __launch_bounds__(64) void k9_fuse(const float* __restrict__ enn, const float* __restrict__ bic,
  const float* __restrict__ W_fuse, const float* __restrict__ b_fuse, float* __restrict__ fused)
{
  int gt = blockIdx.x*64 + threadIdx.x;
  int bb = gt & 31, m = gt >> 5;
  const float* er = enn + bb*1024;
  const float* br = bic + bb*1024;
  const float* wr = W_fuse + (size_t)m*2048;
  float a = 0;
  for (int jj=0;jj<1024;jj+=4){
    float4 e4 = *(const float4*)&er[jj];
    float4 w4 = *(const float4*)&wr[jj];
    a=fmaf(e4.x,w4.x,a); a=fmaf(e4.y,w4.y,a); a=fmaf(e4.z,w4.z,a); a=fmaf(e4.w,w4.w,a);
  }
  for (int jj=0;jj<1024;jj+=4){
    float4 b4 = *(const float4*)&br[jj];
    float4 w4 = *(const float4*)&wr[1024+jj];
    a=fmaf(b4.x,w4.x,a); a=fmaf(b4.y,w4.y,a); a=fmaf(b4.z,w4.z,a); a=fmaf(b4.w,w4.w,a);
  }
  fused[bb*1024 + m] = a + b_fuse[m];
}

// ---------------- K10: output = fused@W_proj.T + b_proj
__global__ __launch_bounds__(64) void k10_proj(const float* __restrict__ fused,
  const float* __restrict__ W_proj, const float* __restrict__ b_proj, float* __restrict__ outp)
{
  int gt = blockIdx.x*64 + threadIdx.x;
  int bb = gt & 31, m = gt >> 5;
  const float* fr = fused + bb*1024;
  const float* wr = W_proj + (size_t)m*1024;
  float a = 0;
  for (int jj=0;jj<1024;jj+=4){
    float4 f4 = *(const float4*)&fr[jj];
    float4 w4 = *(const float4*)&wr[jj];
    a=fmaf(f4.x,w4.x,a); a=fmaf(f4.y,w4.y,a); a=fmaf(f4.z,w4.z,a); a=fmaf(f4.w,w4.w,a);
  }
  outp[bb*1024 + m] = a + b_proj[m];
}

extern "C" void kernel_launch(void* const* d_in, const int* in_sizes, int n_in,
                              void* d_out, int out_size, void* d_ws, size_t ws_size,
                              hipStream_t stream)
{
  const float* x       = (const float*)d_in[0];
  const float* noise   = (const float*)d_in[1];
  const float* W_emb   = (const float*)d_in[2];
  const float* b_emb   = (const float*)d_in[3];
  const float* w_ih    = (const float*)d_in[4];
  const float* w_hh    = (const float*)d_in[5];
  const float* b_ih    = (const float*)d_in[6];
  const float* b_hh    = (const float*)d_in[7];
  const float* w_in    = (const float*)d_in[8];
  const float* b_in    = (const float*)d_in[9];
  const float* w_out   = (const float*)d_in[10];
  const float* b_out   = (const float*)d_in[11];
  const float* W_fix   = (const float*)d_in[12];
  const float* W_inp   = (const float*)d_in[13];
  const float* b_inp   = (const float*)d_in[14];
  const float* conv_w  = (const float*)d_in[15];
  const float* conv_b  = (const float*)d_in[16];
  const float* W_bout  = (const float*)d_in[17];
  const float* b_bout  = (const float*)d_in[18];
  const float* decay   = (const float*)d_in[19];
  const float* W_fuse  = (const float*)d_in[20];
  const float* b_fuse  = (const float*)d_in[21];
  const float* W_proj  = (const float*)d_in[22];
  const float* b_proj  = (const float*)d_in[23];

  float* out       = (float*)d_out;
  float* enn_out   = out + 32768;
  float* bicep_out = out + 65536;
  float* attn_out  = out + 98304;

  float* ws    = (float*)d_ws;
  float* fb    = ws;                    // 32000
  float* ns    = ws + 32000;            // 2,048,000
  unsigned short* preh  = (unsigned short*)(ws + 2080000);   // 8,192,000 u16
  unsigned short* lstmT = (unsigned short*)(ws + 10272000);  // 2,048,000 u16
  float* ctx   = ws + 12320000;         // 2,097,152
  float* S0    = ws + 14417152;         // 32000
  float* S1    = ws + 14449152;
  float* S2    = ws + 14481152;
  float* agg   = ws + 14513152;
  float* fused = ws + 14545152;         // 32768
  unsigned short* Qb = (unsigned short*)(ws + 14577920);  // 2,097,152 u16 each
  unsigned short* Kb = Qb + 2097152;
  unsigned short* Vt = Kb + 2097152;

  k1_emb<<<1016, 256, 0, stream>>>(x, W_emb, b_emb, W_inp, b_inp, ns, fb);
  k2_pre<<<500, 256, 0, stream>>>(ns, w_ih, b_ih, b_hh, preh);
  k3_lstm_sde<<<133, 256, 0, stream>>>(preh, lstmT, w_hh, noise, fb, conv_w, decay, S0, S1, S2);
  k4_qkv<<<256, 256, 0, stream>>>(lstmT, w_in, b_in, Qb, Kb, Vt);
  k5_attn<<<dim3(32,16), 256, 0, stream>>>(Qb, Kb, Vt, attn_out, ctx);
  k6_enn<<<32, 256, 0, stream>>>(ctx, w_out, b_out, W_fix, enn_out);
  k7_agg<<<126, 256, 0, stream>>>(S0, S1, S2, conv_b, agg);
  k8_bicep<<<512, 64, 0, stream>>>(agg, W_bout, b_bout, bicep_out);
  k9_fuse<<<512, 64, 0, stream>>>(enn_out, bicep_out, W_fuse, b_fuse, fused);
  k10_proj<<<512, 64, 0, stream>>>(fused, W_proj, b_proj, out);
}